// Round 18
// baseline (181.270 us; speedup 1.0000x reference)
//
#include <hip/hip_runtime.h>
#include <cstdint>

// Problem constants
constexpr int BB   = 2;
constexpr int SS   = 2048;
constexpr int DD   = 768;
constexpr int HH   = 12;
constexpr int NTOK = BB * SS;          // 4096
constexpr int KSEL = 409;              // int((1-0.8)*2048)
constexpr int KPAD = 448;              // 7 kv-tiles of 64
constexpr int NKT  = 7;                // kv tiles of 64 keys

typedef __bf16 bf16x8 __attribute__((ext_vector_type(8)));
typedef float  f32x4  __attribute__((ext_vector_type(4)));

__device__ __forceinline__ float b2f(unsigned short u) {
  return __uint_as_float(((unsigned)u) << 16);
}
__device__ __forceinline__ unsigned short f2b(float f) {
  unsigned u = __float_as_uint(f);
  u += 0x7fffu + ((u >> 16) & 1u);   // RNE
  return (unsigned short)(u >> 16);
}
__device__ __forceinline__ unsigned long long shfl_xor_u64(unsigned long long v, int m) {
  unsigned lo = (unsigned)v, hi = (unsigned)(v >> 32);
  lo = __shfl_xor(lo, m, 64);
  hi = __shfl_xor(hi, m, 64);
  return ((unsigned long long)hi << 32) | lo;
}

__device__ __forceinline__ void gload_lds16(const void* gsrc, void* ldst) {
  __builtin_amdgcn_global_load_lds(
      (__attribute__((address_space(1))) void*)(gsrc),
      (__attribute__((address_space(3))) void*)(ldst), 16, 0, 0);
}

// ------- mega_pre: prep_imp (2048) | weight transpose (6912) | gate1 (32) ---
__global__ __launch_bounds__(256) void mega_pre(
    const float* __restrict__ x, const float* __restrict__ wsp,
    const float* __restrict__ bsp,
    unsigned short* __restrict__ xb, unsigned short* __restrict__ xpb,
    float* __restrict__ imp,
    const float* w0, const float* w1, const float* w2, const float* w3,
    const float* w4, const float* w5, const float* w6, const float* w7,
    const float* w8, const float* w9,
    const float* __restrict__ gg, const float* __restrict__ lgam,
    const float* __restrict__ tg,
    const float* __restrict__ gb, const float* __restrict__ lbet,
    const float* __restrict__ tb,
    unsigned short* __restrict__ WTx4, unsigned short* __restrict__ WTkv,
    unsigned short* __restrict__ WTqt, unsigned short* __restrict__ WTtkv,
    unsigned short* __restrict__ WTo,
    float* __restrict__ Sbuf, float* __restrict__ Tbuf,
    float* __restrict__ partial) {
  __shared__ float tile[32][33];
  __shared__ float gsh[32], bsh[32];
  __shared__ float redS[8][32], redT[8][32];
  int id = blockIdx.x;
  int tid = threadIdx.x;

  if (id < SS) {
    int srow = id;
    const float* xr0 = x + (long)srow * DD;
    const float* xr1 = x + (long)(SS + srow) * DD;
    float acc0 = 0.f, acc1 = 0.f;
#pragma unroll
    for (int k = 0; k < 3; ++k) {
      int c = tid + k * 256;
      int j2 = c & ~1;
      float freq = __expf((float)j2 * -0.011992630692677323f);
      float ang = (float)srow * freq;
      float pe = (c & 1) ? __cosf(ang) : __sinf(ang);
      float w = wsp[c];
      float x0 = xr0[c], x1 = xr1[c];
      xb[(long)srow * DD + c]        = f2b(x0);
      xb[(long)(SS + srow) * DD + c] = f2b(x1);
      xpb[(long)srow * DD + c]        = f2b(x0 + pe);
      xpb[(long)(SS + srow) * DD + c] = f2b(x1 + pe);
      acc0 += x0 * w;
      acc1 += x1 * w;
    }
#pragma unroll
    for (int m = 1; m < 64; m <<= 1) {
      acc0 += __shfl_xor(acc0, m, 64);
      acc1 += __shfl_xor(acc1, m, 64);
    }
    __shared__ float red[8];
    int wv = tid >> 6, lane = tid & 63;
    if (lane == 0) { red[wv] = acc0; red[4 + wv] = acc1; }
    __syncthreads();
    if (tid == 0) {
      imp[srow]      = red[0] + red[1] + red[2] + red[3] + bsp[0];
      imp[SS + srow] = red[4] + red[5] + red[6] + red[7] + bsp[0];
    }
  } else if (id < SS + 6912) {
    int tidx = id - SS;
    int z, bx, by;
    if (tidx < 5184) { z = tidx / 576; int rem = tidx % 576; by = rem / 24; bx = rem % 24; }
    else             { z = 9; int rem = tidx - 5184; by = rem / 24; bx = rem % 24; }
    const float* srcs[10] = {w0, w1, w2, w3, w4, w5, w6, w7, w8, w9};
    const float* src = srcs[z];
    unsigned short* dst;
    int R = DD;
    switch (z) {
      case 0: dst = WTx4;                       break;
      case 1: dst = WTkv;                       break;
      case 2: dst = WTkv + (long)DD * DD;       break;
      case 3: dst = WTx4 + (long)DD * DD;       break;
      case 4: dst = WTx4 + (long)2 * DD * DD;   break;
      case 5: dst = WTx4 + (long)3 * DD * DD;   break;
      case 6: dst = WTqt;                       break;
      case 7: dst = WTtkv;                      break;
      case 8: dst = WTtkv + (long)DD * DD;      break;
      default: dst = WTo; R = 2304;             break;
    }
    int r0 = by * 32, c0 = bx * 32;
    int tx = tid & 31, ty = tid >> 5;
    for (int i = ty; i < 32; i += 8) tile[i][tx] = src[(long)(r0 + i) * DD + c0 + tx];
    if (z == 9 && ty == 0) {
      int kk = r0 + tx;                    // tile is single-branch (768 % 32 == 0)
      gsh[tx] = (kk < 768) ? gg[kk] : (kk < 1536) ? lgam[kk - 768] : tg[kk - 1536];
      bsh[tx] = (kk < 768) ? gb[kk] : (kk < 1536) ? lbet[kk - 768] : tb[kk - 1536];
    }
    __syncthreads();
    if (z == 9) {
      float gamv = gsh[tx];
      for (int i = ty; i < 32; i += 8)
        dst[(long)(c0 + i) * R + r0 + tx] = f2b(tile[tx][i] * gamv);
      float pS = 0.f, pT = 0.f;
      for (int i = ty; i < 32; i += 8) {
        float wv = tile[i][tx];
        pS += gsh[i] * wv;
        pT += bsh[i] * wv;
      }
      redS[ty][tx] = pS; redT[ty][tx] = pT;
      __syncthreads();
      if (ty == 0) {
        float s = 0.f, t2 = 0.f;
#pragma unroll
        for (int j = 0; j < 8; ++j) { s += redS[j][tx]; t2 += redT[j][tx]; }
        int br = r0 / 768;
        atomicAdd(&Sbuf[br * DD + c0 + tx], s);
        atomicAdd(&Tbuf[br * DD + c0 + tx], t2);
      }
    } else {
      for (int i = ty; i < 32; i += 8)
        dst[(long)(c0 + i) * R + r0 + tx] = f2b(tile[tx][i]);
    }
  } else {
    int rem = id - SS - 6912;            // 0..31
    int chunk = rem & 15, b = rem >> 4;
    for (int c = tid; c < DD; c += 256) {
      const float* xp = x + ((long)(b * SS + chunk * 128)) * DD + c;
      float acc = 0.f;
      for (int s2 = 0; s2 < 128; ++s2) acc += xp[(long)s2 * DD];
      partial[(long)(b * 16 + chunk) * DD + c] = acc;
    }
  }
}

// ------- fused: sel-free GEMM tiles (0..971) | topk (972..973) | gate2 ------
// blocks 0..971 use threads 0..255 (rest exit). LDS unioned at 32 KB.
__global__ __launch_bounds__(1024) void gemm_topk(
    const unsigned short* __restrict__ xb,    const unsigned short* __restrict__ WTx4,
    unsigned short* __restrict__ QKV4,
    const unsigned short* __restrict__ xpb,   const unsigned short* __restrict__ WTqt,
    unsigned short* __restrict__ Qt,
    const unsigned short* __restrict__ WTtkv,
    unsigned short* __restrict__ K8, unsigned short* __restrict__ Vt8,
    unsigned short* __restrict__ Vtl,
    const float* __restrict__ imp, int* __restrict__ sel,
    const float* __restrict__ partial, const float* __restrict__ w_gate,
    const float* __restrict__ b_gate, float* __restrict__ fw) {
  __shared__ unsigned long long smem_u64[4096];   // 32 KB union
  int id = blockIdx.x;
  int tid = threadIdx.x;

  if (id < 972) {
    // ------------- GEMM tiles (regions 0: QKV4, 2: Qt, 3: T8) --------------
    if (tid >= 256) return;
    unsigned short* AsB = (unsigned short*)smem_u64;   // [2][4096]
    unsigned short* BsB = AsB + 8192;
    constexpr int K = DD;
    const int lane = tid & 63;
    const int wv = tid >> 6;
    const int wr = wv >> 1, wc = wv & 1;

    const unsigned short* BT;
    int ntx, tile, region;
    if (id < 768) {
      region = 0; BT = WTx4; ntx = 24;
      int xcd = id & 7, idx = id >> 3;   // idx in [0,96)
      int r = (xcd >> 2) * 16 + (idx & 15);
      int c = (xcd & 3) * 6 + (idx >> 4);
      tile = r * 24 + c;
    } else {
      int e = id - 768;                  // 0..203
      if (e < 192) { region = 2; BT = WTqt;  ntx = 6;  tile = e; }
      else         { region = 3; BT = WTtkv; ntx = 12; tile = e - 192; }
    }
    const long rowBase = (long)(tile / ntx) * 128;
    const long colBase = (long)(tile % ntx) * 128;

    auto arow = [&](int r) -> const unsigned short* {
      long grow = rowBase + r;
      if (region == 0) return xb + grow * (long)K;
      if (region == 2) return xpb + grow * (long)K;
      if (grow < 16) {
        int bb2 = (int)grow >> 3, j = ((int)grow & 7) * 256;
        return xpb + ((long)bb2 * SS + j) * (long)K;
      }
      return xpb;   // T8 rows >=16 never stored
    };

    f32x4 acc[4][4];
#pragma unroll
    for (int i = 0; i < 4; ++i)
#pragma unroll
      for (int j = 0; j < 4; ++j)
#pragma unroll
        for (int r = 0; r < 4; ++r) acc[i][j][r] = 0.f;

    const int g0 = tid, g1 = tid + 256;
    const int r0 = g0 >> 2, k80 = (g0 & 3) ^ ((r0 >> 1) & 3);
    const int r1 = g1 >> 2, k81 = (g1 & 3) ^ ((r1 >> 1) & 3);
    const unsigned short* ga0 = arow(r0) + k80 * 8;
    const unsigned short* ga1 = arow(r1) + k81 * 8;
    const unsigned short* gb0 = BT + (colBase + r0) * (long)K + k80 * 8;
    const unsigned short* gb1 = BT + (colBase + r1) * (long)K + k81 * 8;

    const int k8 = lane >> 4;
    const int fr = lane & 15;
    int aoff[4], boff[4];
#pragma unroll
    for (int i = 0; i < 4; ++i) {
      int rowA = wr * 64 + i * 16 + fr;
      aoff[i] = (rowA * 4 + (k8 ^ ((rowA >> 1) & 3))) * 8;
      int rowB = wc * 64 + i * 16 + fr;
      boff[i] = (rowB * 4 + (k8 ^ ((rowB >> 1) & 3))) * 8;
    }

    auto stage = [&](int buf, int t) {
      int ko = t * 32;
      gload_lds16(ga0 + ko, &AsB[buf * 4096 + g0 * 8]);
      gload_lds16(ga1 + ko, &AsB[buf * 4096 + g1 * 8]);
      gload_lds16(gb0 + ko, &BsB[buf * 4096 + g0 * 8]);
      gload_lds16(gb1 + ko, &BsB[buf * 4096 + g1 * 8]);
    };

    constexpr int nk = K >> 5;   // 24
    stage(0, 0);
    __syncthreads();
    for (int t = 0; t < nk; ++t) {
      int cur = t & 1;
      if (t + 1 < nk) stage(cur ^ 1, t + 1);
      bf16x8 af[4], bfr[4];
#pragma unroll
      for (int i = 0; i < 4; ++i) af[i] = *(const bf16x8*)(&AsB[cur * 4096 + aoff[i]]);
#pragma unroll
      for (int i = 0; i < 4; ++i) bfr[i] = *(const bf16x8*)(&BsB[cur * 4096 + boff[i]]);
#pragma unroll
      for (int mi = 0; mi < 4; ++mi)
#pragma unroll
        for (int ni = 0; ni < 4; ++ni)
          acc[mi][ni] = __builtin_amdgcn_mfma_f32_16x16x32_bf16(af[mi], bfr[ni], acc[mi][ni], 0, 0, 0);
      __syncthreads();
    }

    int mode, vcol0 = 0, N = 0;
    unsigned short* C = nullptr;
    if (region == 0)      { mode = (colBase >= 2304) ? 1 : 0; C = QKV4; N = 3072;
                            vcol0 = (int)colBase - 2304; }
    else if (region == 2) { mode = 0; C = Qt; N = 768; }
    else                  { mode = (colBase >= 768) ? 4 : 3;
                            vcol0 = (int)colBase - 768; }

    const int orow0 = (lane >> 4) * 4;
    if (mode == 0) {
#pragma unroll
      for (int mi = 0; mi < 4; ++mi) {
        long gr = rowBase + wr * 64 + mi * 16 + orow0;
#pragma unroll
        for (int ni = 0; ni < 4; ++ni) {
          long gc = colBase + wc * 64 + ni * 16 + fr;
#pragma unroll
          for (int r = 0; r < 4; ++r)
            C[(gr + r) * (long)N + gc] = f2b(acc[mi][ni][r]);
        }
      }
    } else {
#pragma unroll
      for (int mi = 0; mi < 4; ++mi) {
        int lr = wr * 64 + mi * 16 + orow0;
        int grow = (int)rowBase + lr;
#pragma unroll
        for (int ni = 0; ni < 4; ++ni) {
          int lc = wc * 64 + ni * 16 + fr;
          uint2 pk;
          pk.x = (unsigned)f2b(acc[mi][ni][0]) | ((unsigned)f2b(acc[mi][ni][1]) << 16);
          pk.y = (unsigned)f2b(acc[mi][ni][2]) | ((unsigned)f2b(acc[mi][ni][3]) << 16);
          if (mode == 1) {         // QKV4 v_l -> Vtl[b][c][s]
            int bb2 = grow >> 11, s = grow & (SS - 1);
            *(uint2*)(Vtl + ((long)bb2 * DD + vcol0 + lc) * SS + s) = pk;
          } else if (mode == 3) {  // T8 k -> K8[b][16][768] rows 0..7 per b
            if (grow < 16) {
#pragma unroll
              for (int r = 0; r < 4; ++r) {
                int g2 = grow + r;
                K8[((long)(g2 >> 3) * 16 + (g2 & 7)) * DD + colBase + lc] =
                    f2b(acc[mi][ni][r]);
              }
            }
          } else {                 // mode 4: T8 v -> Vt8[b][c][32] j 0..7
            if (grow < 16) {
              *(uint2*)(Vt8 + ((long)(grow >> 3) * DD + vcol0 + lc) * 32 + (grow & 7)) = pk;
            }
          }
        }
      }
      if (mode == 4) {             // zero Vt8 j=8..31
#pragma unroll
        for (int e = 0; e < 6; ++e) {
          int id2 = tid + e * 256;
          int bb2 = id2 / 768, rem = id2 % 768;
          int c = rem / 6, ch = rem % 6;
          *(uint2*)(Vt8 + ((long)bb2 * DD + vcol0 + c) * 32 + 8 + ch * 4) = uint2{0u, 0u};
        }
      }
    }
  } else if (id < 974) {
    // ------------- topk: hybrid bitonic sort (value desc, index asc) -------
    unsigned long long* keys = smem_u64;   // [2048]
    int b = id - 972;
    for (int i = tid; i < SS; i += 1024) {
      float v = imp[b * SS + i];
      unsigned u = __float_as_uint(v);
      u = (u & 0x80000000u) ? ~u : (u | 0x80000000u);
      unsigned du = ~u;
      keys[i] = ((unsigned long long)du << 32) | (unsigned)i;
    }
    __syncthreads();
    for (int k = 2; k <= SS; k <<= 1) {
      for (int j = k >> 1; j >= 64; j >>= 1) {
        for (int i = tid; i < SS; i += 1024) {
          int p = i ^ j;
          if (p > i) {
            unsigned long long a = keys[i], bb = keys[p];
            bool up = ((i & k) == 0);
            if ((a > bb) == up) { keys[i] = bb; keys[p] = a; }
          }
        }
        __syncthreads();
      }
      unsigned long long k0 = keys[tid], k1 = keys[tid + 1024];
      bool up0 = ((tid & k) == 0);
      bool up1 = (((tid + 1024) & k) == 0);
      int j0 = (k >> 1) < 32 ? (k >> 1) : 32;
      for (int j = j0; j >= 1; j >>= 1) {
        bool low = ((tid & j) == 0);
        unsigned long long p0 = shfl_xor_u64(k0, j);
        k0 = ((low == up0) == (k0 < p0)) ? k0 : p0;
        unsigned long long p1 = shfl_xor_u64(k1, j);
        k1 = ((low == up1) == (k1 < p1)) ? k1 : p1;
      }
      keys[tid] = k0; keys[tid + 1024] = k1;
      __syncthreads();
    }
    for (int i = tid; i < KSEL; i += 1024) sel[b * KSEL + i] = (int)(keys[i] & 0xffffffffu);
  } else {
    // ------------- gate2 ---------------------------------------------------
    float* meanbuf = (float*)smem_u64;          // [768]
    float* lg = meanbuf + DD;                   // [3]
    int b = id - 974;
    if (tid < DD) {
      float acc = 0.f;
      for (int p = 0; p < 16; ++p) acc += partial[(long)(b * 16 + p) * DD + tid];
      meanbuf[tid] = acc * (1.0f / (float)SS);
    }
    __syncthreads();
    if (tid < 3) {
      float acc = b_gate[tid];
      for (int d = 0; d < DD; ++d) acc += meanbuf[d] * w_gate[d * 3 + tid];
      lg[tid] = acc;
    }
    __syncthreads();
    if (tid == 0) {
      float mx = fmaxf(lg[0], fmaxf(lg[1], lg[2]));
      float e0 = expf(lg[0] - mx), e1 = expf(lg[1] - mx), e2 = expf(lg[2] - mx);
      float inv = 1.f / (e0 + e1 + e2);
      fw[b * 3 + 0] = e0 * inv; fw[b * 3 + 1] = e1 * inv; fw[b * 3 + 2] = e2 * inv;
    }
  }
}

// ------- KVg projection (84 tiles, needs sel): K half + transposed V --------
__global__ __launch_bounds__(256) void gemm_kvg(
    const unsigned short* __restrict__ xb, const unsigned short* __restrict__ WTkv,
    unsigned short* __restrict__ KVg, const int* __restrict__ sel,
    unsigned short* __restrict__ Vt) {
  __shared__ unsigned short AsB[2][4096];
  __shared__ unsigned short BsB[2][4096];
  constexpr int K = DD;
  const int tid = threadIdx.x;
  const int lane = tid & 63;
  const int wv = tid >> 6;
  const int wr = wv >> 1, wc = wv & 1;

  int tile = blockIdx.x;                 // 84 = 7 row-tiles x 12 col-tiles
  const long rowBase = (long)(tile / 12) * 128;
  const long colBase = (long)(tile % 12) * 128;

  auto arow = [&](int r) -> const unsigned short* {
    long grow = rowBase + r;
    int bb2 = (int)(grow / KPAD), j = (int)(grow % KPAD);
    int srow = (j < KSEL) ? sel[bb2 * KSEL + j] : 0;
    return xb + ((long)bb2 * SS + srow) * (long)K;
  };

  f32x4 acc[4][4];
#pragma unroll
  for (int i = 0; i < 4; ++i)
#pragma unroll
    for (int j = 0; j < 4; ++j)
#pragma unroll
      for (int r = 0; r < 4; ++r) acc[i][j][r] = 0.f;

  const int g0 = tid, g1 = tid + 256;
  const int r0 = g0 >> 2, k80 = (g0 & 3) ^ ((r0 >> 1) & 3);
  const int r1 = g1 >> 2, k81 = (g1 & 3) ^ ((r1 >> 1) & 3);
  const unsigned short* ga0 = arow(r0) + k80 * 8;
  const unsigned short* ga1 = arow(r1) + k81 * 8;
  const unsigned short* gb0 = WTkv + (colBase + r0) * (long)K + k80 * 8;
  const unsigned short* gb1 = WTkv + (colBase + r1) * (long)K + k81 * 8;

  const int k8 = lane >> 4;
  const int fr = lane & 15;
  int aoff[4], boff[4];
#pragma unroll
  for (int i = 0; i < 4; ++i) {
    int rowA = wr * 64 + i * 16 + fr;
    aoff[i] = (rowA * 4 + (k8 ^ ((rowA >> 1) & 3))) * 8;
    int rowB = wc * 64 + i * 16 + fr;
    boff[i] = (rowB * 4 + (k8 ^ ((rowB >> 1) & 3))) * 8;
  }

  auto stage = [&](int buf, int t) {
    int ko = t * 32;
    gload_lds16(ga0 + ko, &AsB[buf][g0 * 8]);
    gload_lds16(ga1 + ko, &AsB[buf][g1 * 8]);
    gload_lds16(gb0 + ko, &BsB[buf][g0 * 8]);
    gload_lds16(gb1 + ko, &BsB[buf][g1 * 8]);
  };

  constexpr int nk = K >> 5;   // 24
  stage(0, 0);
  __syncthreads();
  for (int t = 0; t < nk; ++t) {
    int cur = t & 1;
    if (t + 1 < nk) stage(cur ^ 1, t + 1);
    bf16x8 af[4], bfr[4];
#pragma unroll
    for (int i = 0; i < 4; ++i) af[i] = *(const bf16x8*)(&AsB[cur][aoff[i]]);
#pragma unroll
    for (int i = 0; i < 4; ++i) bfr[i] = *(const bf16x8*)(&BsB[cur][boff[i]]);
#pragma unroll
    for (int mi = 0; mi < 4; ++mi)
#pragma unroll
      for (int ni = 0; ni < 4; ++ni)
        acc[mi][ni] = __builtin_amdgcn_mfma_f32_16x16x32_bf16(af[mi], bfr[ni], acc[mi][ni], 0, 0, 0);
    __syncthreads();
  }

  const int orow0 = (lane >> 4) * 4;
  if (colBase < 768) {                   // K half -> KVg rows
#pragma unroll
    for (int mi = 0; mi < 4; ++mi) {
      long gr = rowBase + wr * 64 + mi * 16 + orow0;
#pragma unroll
      for (int ni = 0; ni < 4; ++ni) {
        long gc = colBase + wc * 64 + ni * 16 + fr;
#pragma unroll
        for (int r = 0; r < 4; ++r)
          KVg[(gr + r) * 1536L + gc] = f2b(acc[mi][ni][r]);
      }
    }
  } else {                               // V half -> Vt[b][c][j] transposed
    int vcol0 = (int)colBase - 768;
#pragma unroll
    for (int mi = 0; mi < 4; ++mi) {
      int grow = (int)rowBase + wr * 64 + mi * 16 + orow0;
      int bb2 = grow / KPAD, j = grow - bb2 * KPAD;
#pragma unroll
      for (int ni = 0; ni < 4; ++ni) {
        int lc = wc * 64 + ni * 16 + fr;
        uint2 pk;
        pk.x = (unsigned)f2b(acc[mi][ni][0]) | ((unsigned)f2b(acc[mi][ni][1]) << 16);
        pk.y = (unsigned)f2b(acc[mi][ni][2]) | ((unsigned)f2b(acc[mi][ni][3]) << 16);
        *(uint2*)(Vt + ((long)bb2 * DD + vcol0 + lc) * KPAD + j) = pk;
      }
    }
  }
}

// ---------------- final GEMM, split-K=3 into f32 partials -------------------
__global__ __launch_bounds__(256) void gemm_final_sk(const unsigned short* __restrict__ A,
                                                     const unsigned short* __restrict__ BT,
                                                     float* __restrict__ Cpart) {
  __shared__ unsigned short As[2][128 * 32];
  __shared__ unsigned short Bs[2][128 * 32];
  constexpr int N = 768, K = 2304, CK = 768;
  const int tid = threadIdx.x;
  const int lane = tid & 63;
  const int wv = tid >> 6;
  const int wr = wv >> 1, wc = wv & 1;
  const int z = blockIdx.z;

  int lin = blockIdx.y * gridDim.x + blockIdx.x;   // 192 blocks/plane
  int swz = (lin & 7) * 24 + (lin >> 3);
  const long rowBase = (long)(swz / 6) * 128;
  const long colBase = (long)(swz % 6) * 128;

  f32x4 acc[4][4];
#pragma unroll
  for (int i = 0; i < 4; ++i)
#pragma unroll
    for (int j = 0; j < 4; ++j)
#pragma unroll
      for (int r = 0; r < 4; ++r) acc[i][j][r] = 0.f;

  const int g0 = tid, g1 = tid + 256;
  const int r0 = g0 >> 2, k80 = (g0 & 3) ^ ((r0 >> 1) & 3);
  const int r1 = g1 >> 2, k81 = (g1 & 3) ^ ((r1 >> 1) & 3);
  const unsigned short* ga0 = A + (rowBase + r0) * (long)K + z * CK + k80 * 8;
  const unsigned short* ga1 = A + (rowBase + r1) * (long)K + z * CK + k81 * 8;
  const unsigned short* gb0 = BT + (colBase + r0) * (long)K + z * CK + k80 * 8;
  const unsigned short* gb1 = BT + (colBase + r1) * (long)K + z * CK + k81 * 8;

  const int k8 = lane >> 4;
  const int fr = lane & 15;
  int aoff[4], boff[4];
#pragma unroll
  for (int i = 0; i < 4; ++i) {
    int rowA = wr * 64 + i * 16 + fr;
    aoff[i] = (rowA * 4 + (k8 ^ ((rowA >> 1) & 3))) * 8;
    int rowB = wc * 64 + i * 16 + fr;
    boff[i] = (rowB * 4 + (k8 ^ ((rowB >> 1) & 3))) * 8;
  }

  auto stage = [&](int buf, int t) {
    int ko = t * 32;
    gload_lds16(ga0 + ko, &As[buf][g0 * 8]);
    gload_lds16(ga1 + ko, &As[buf][g1 * 8]);
    gload_lds16(gb0 + ko, &Bs[buf][g0 * 8]);
    gload_lds16(gb1 + ko, &Bs[buf][g1 * 8]);
  };

  constexpr int nk = CK >> 5;   // 24
  stage(0, 0);
  __syncthreads();
  for (int t = 0; t < nk; ++t) {
    int cur = t & 1;
    if (t + 1 < nk) stage(cur ^ 1, t + 1);
    bf16x8 af[4], bfr[4];
#pragma unroll
    for (int i = 0; i < 4; ++i) af[i] = *(const bf16x8*)(&As[cur][aoff[i]]);
#pragma unroll
    for (int i = 0; i < 4; ++i) bfr[i] = *(const bf16x8*)(&Bs[cur][boff[i]]);
#pragma unroll
    for (int mi = 0; mi < 4; ++mi)
#pragma unroll
      for (int ni = 0; ni < 4; ++ni)
        acc[mi][ni] = __builtin_amdgcn_mfma_f32_16x16x32_bf16(af[mi], bfr[ni], acc[mi][ni], 0, 0, 0);
    __syncthreads();
  }

  float* Cz = Cpart + (long)z * NTOK * DD;
  const int orow0 = (lane >> 4) * 4;
#pragma unroll
  for (int mi = 0; mi < 4; ++mi) {
    long gr = rowBase + wr * 64 + mi * 16 + orow0;
#pragma unroll
    for (int ni = 0; ni < 4; ++ni) {
      long gc = colBase + wc * 64 + ni * 16 + fr;
#pragma unroll
      for (int r = 0; r < 4; ++r)
        Cz[(gr + r) * (long)N + gc] = acc[mi][ni][r];
    }
  }
}

// ------- reduce partials, applying the folded-LN affine per branch ----------
__global__ __launch_bounds__(256) void reduce_out(const float* __restrict__ P,
                                                  const float* __restrict__ bias,
                                                  const float* __restrict__ sumb,
                                                  const float* __restrict__ sqb,
                                                  const float* __restrict__ Sbuf,
                                                  const float* __restrict__ Tbuf,
                                                  const float* __restrict__ fw,
                                                  float* __restrict__ out) {
  long i = (long)blockIdx.x * 256 + threadIdx.x;   // over NTOK*DD/4 f32x4
  int r = (int)(i / (DD / 4));
  int c4 = (int)(i % (DD / 4));
  int b = r >> 11;
  f32x4 o = *(const f32x4*)(bias + c4 * 4);
#pragma unroll
  for (int br = 0; br < 3; ++br) {
    float sum = sumb[br * NTOK + r];
    float sq  = sqb[br * NTOK + r];
    float mean = sum * (1.f / (float)DD);
    float var  = sq * (1.f / (float)DD) - mean * mean;
    float rs   = rsqrtf(var + 1e-5f);
    float gate = fw[b * 3 + br];
    f32x4 P4 = ((const f32x4*)(P + (long)br * NTOK * DD))[i];
    f32x4 S4 = *(const f32x4*)(Sbuf + br * DD + c4 * 4);
    f32x4 T4 = *(const f32x4*)(Tbuf + br * DD + c4 * 4);
#pragma unroll
    for (int e = 0; e < 4; ++e)
      o[e] += gate * (rs * (P4[e] - mean * S4[e]) + T4[e]);
  }
  ((f32x4*)out)[i] = o;
}

// ---------------- attention bodies (raw bf16 output + row stats) ------------
__device__ __forceinline__ void attn_flash_body(
    const unsigned short* __restrict__ QKV4,
    const unsigned short* __restrict__ KVg,
    const unsigned short* __restrict__ Vt,
    unsigned short* __restrict__ comb,
    float* __restrict__ sumb, float* __restrict__ sqb,
    unsigned short* smem) {
  unsigned short* Kl = smem;            // [2][64*64]
  unsigned short* Vl = smem + 8192;     // [2][64*64]
  unsigned short* Pl = smem + 16384;    // [4][16*68]
  int tid = threadIdx.x, w = tid >> 6, lane = tid & 63;
  int fr = lane & 15, g = lane >> 4;
  int b = blockIdx.y / HH, h = blockIdx.y % HH, hoff = h * 64;
  int qbase = blockIdx.x * 64 + w * 16;
  long qrow = (long)b * SS + qbase + fr;

  const unsigned short* qptr = QKV4 + qrow * 3072 + hoff + g * 8;
  bf16x8 bq0 = *(const bf16x8*)(qptr);
  bf16x8 bq1 = *(const bf16x8*)(qptr + 32);

  const int s0 = tid, s1 = tid + 256;
  const int r0 = s0 >> 3, c0 = (s0 & 7) ^ (r0 & 7);
  const int r1 = s1 >> 3, c1 = (s1 & 7) ^ (r1 & 7);
  const unsigned short* kg_b = KVg + (long)b * KPAD * 1536 + hoff;
  const unsigned short* vt_b = Vt + ((long)b * DD + hoff) * KPAD;

  auto stage = [&](int buf, int t0) {
    gload_lds16(kg_b + (long)(t0 * 64 + r0) * 1536 + c0 * 8, &Kl[buf * 4096 + s0 * 8]);
    gload_lds16(kg_b + (long)(t0 * 64 + r1) * 1536 + c1 * 8, &Kl[buf * 4096 + s1 * 8]);
    gload_lds16(vt_b + (long)r0 * KPAD + t0 * 64 + c0 * 8, &Vl[buf * 4096 + s0 * 8]);
    gload_lds16(vt_b + (long)r1 * KPAD + t0 * 64 + c1 * 8, &Vl[buf * 4096 + s1 * 8]);
  };

  f32x4 oacc[4];
#pragma unroll
  for (int mf = 0; mf < 4; ++mf)
#pragma unroll
    for (int r = 0; r < 4; ++r) oacc[mf][r] = 0.f;
  float m = -3.0e38f, l = 0.f;

  stage(0, 0);
  asm volatile("s_waitcnt vmcnt(0)" ::: "memory");
  __syncthreads();

  for (int t = 0; t < NKT; ++t) {
    int cur = t & 1;
    if (t + 1 < NKT) stage(cur ^ 1, t + 1);

    f32x4 st[4];
#pragma unroll
    for (int kt = 0; kt < 4; ++kt) {
      int row = kt * 16 + fr;
      bf16x8 a0 = *(const bf16x8*)(&Kl[cur * 4096 + (row * 8 + (g ^ (row & 7))) * 8]);
      bf16x8 a1 = *(const bf16x8*)(&Kl[cur * 4096 + (row * 8 + ((4 + g) ^ (row & 7))) * 8]);
      f32x4 z = {0.f, 0.f, 0.f, 0.f};
      z = __builtin_amdgcn_mfma_f32_16x16x32_bf16(a0, bq0, z, 0, 0, 0);
      st[kt] = __builtin_amdgcn_mfma_f32_16x16x32_bf16(a1, bq1, z, 0, 0, 0);
    }

    float tm = -3.0e38f;
#pragma unroll
    for (int kt = 0; kt < 4; ++kt)
#pragma unroll
      for (int r = 0; r < 4; ++r) {
        int key = t * 64 + kt * 16 + g * 4 + r;
        float s = (key < KSEL) ? st[kt][r] * 0.125f : -1.0e30f;
        st[kt][r] = s;
        tm = fmaxf(tm, s);
      }
    tm = fmaxf(tm, __shfl_xor(tm, 16, 64));
    tm = fmaxf(tm, __shfl_xor(tm, 32, 64));
    float newm = fmaxf(m, tm);
    float f = __expf(m - newm);
    float tsum = 0.f;
#pragma unroll
    for (int kt = 0; kt < 4; ++kt)
#pragma unroll
      for (int r = 0; r < 4; ++r) {
        float e = __expf(st[kt][r] - newm);
        st[kt][r] = e;
        tsum += e;
      }
    tsum += __shfl_xor(tsum, 16, 64);
    tsum += __shfl_xor(tsum, 32, 64);
    l = l * f + tsum;
    m = newm;
#pragma unroll
    for (int mf = 0; mf < 4; ++mf)
#pragma unroll
      for (int r = 0; r < 4; ++r) oacc[mf][r] *= f;

    unsigned short* pw = &Pl[w * 1088 + fr * 68 + g * 4];
#pragma unroll
    for (int kt = 0; kt < 4; ++kt) {
      uint2 pk;
      pk.x = (unsigned)f2b(st[kt][0]) | ((unsigned)f2b(st[kt][1]) << 16);
      pk.y = (unsigned)f2b(st[kt][2]) | ((unsigned)f2b(st[kt][3]) << 16);
      *(uint2*)(pw + kt * 16) = pk;
    }

    const unsigned short* prd = &Pl[w * 1088 + fr * 68];
#pragma unroll
    for (int ks2 = 0; ks2 < 2; ++ks2) {
      bf16x8 pf = *(const bf16x8*)(prd + ks2 * 32 + g * 8);
#pragma unroll
      for (int mf = 0; mf < 4; ++mf) {
        int vr = mf * 16 + fr;
        int vc = ks2 * 4 + g;
        bf16x8 vf = *(const bf16x8*)(&Vl[cur * 4096 + (vr * 8 + (vc ^ (vr & 7))) * 8]);
        oacc[mf] = __builtin_amdgcn_mfma_f32_16x16x32_bf16(vf, pf, oacc[mf], 0, 0, 0);
      }
    }

    asm volatile("s_waitcnt vmcnt(0)" ::: "memory");
    __syncthreads();
  }

  float inv = 1.f / l;
  unsigned short* orow = comb + qrow * 2304 + hoff;
  float rsum = 0.f, rsq = 0.f;
#pragma unroll
  for (int mf = 0; mf < 4; ++mf) {
    float v0 = oacc[mf][0] * inv, v1 = oacc[mf][1] * inv;
    float v2 = oacc[mf][2] * inv, v3 = oacc[mf][3] * inv;
    rsum += v0 + v1 + v2 + v3;
    rsq  += v0 * v0 + v1 * v1 + v2 * v2 + v3 * v3;
    uint2 pk;
    pk.x = (unsigned)f2b(v0) | ((unsigned)f2b(v1) << 16);
    pk.y = (unsigned)f2b(v2) | ((unsigned)f2b(v3) << 16);
    *(uint2*)(orow + mf * 16 + g * 4) = pk;
  }
  rsum += __shfl_xor(rsum, 16, 64);
  rsum += __shfl_xor(rsum, 32, 64);
  rsq  += __shfl_xor(rsq, 16, 64);
  rsq  += __shfl_xor(rsq, 32, 64);
  if (lane < 16) {
    atomicAdd(&sumb[qrow], rsum);
    atomicAdd(&sqb[qrow], rsq);
  }
}

__device__ __forceinline__ void attn_win_body(
    const unsigned short* __restrict__ QKV,
    const unsigned short* __restrict__ K8,
    const unsigned short* __restrict__ Vt,
    unsigned short* __restrict__ comb, int brOff,
    float* __restrict__ sumb, float* __restrict__ sqb,
    int LD, int QO, long VSTR, bool local,
    unsigned short* smem) {
  int tid = threadIdx.x, w = tid >> 6, lane = tid & 63;
  int fr = lane & 15, g = lane >> 4;
  int b = blockIdx.y / HH, h = blockIdx.y % HH, hoff = h * 64;
  int qbase = blockIdx.x * 64 + w * 16;
  long qrow = (long)b * SS + qbase + fr;

  const unsigned short* qptr = QKV + qrow * LD + QO + hoff + g * 8;
  bf16x8 bq0 = *(const bf16x8*)(qptr);
  bf16x8 bq1 = *(const bf16x8*)(qptr + 32);

  int kstart = qbase - 8;
  if (kstart < 0) kstart = 0;
  if (kstart > SS - 32) kstart = SS - 32;

  f32x4 st[2];
  if (local) {
#pragma unroll
    for (int kt = 0; kt < 2; ++kt) {
      const unsigned short* kp =
          QKV + ((long)b * SS + kstart + kt * 16 + fr) * LD + 1536 + hoff + g * 8;
      bf16x8 a0 = *(const bf16x8*)(kp);
      bf16x8 a1 = *(const bf16x8*)(kp + 32);
      f32x4 z = {0.f, 0.f, 0.f, 0.f};
      z = __builtin_amdgcn_mfma_f32_16x16x32_bf16(a0, bq0, z, 0, 0, 0);
      st[kt] = __builtin_amdgcn_mfma_f32_16x16x32_bf16(a1, bq1, z, 0, 0, 0);
    }
  } else {
    const unsigned short* kp = K8 + ((long)b * 16 + fr) * DD + hoff + g * 8;
    bf16x8 a0 = *(const bf16x8*)(kp);
    bf16x8 a1 = *(const bf16x8*)(kp + 32);
    f32x4 z = {0.f, 0.f, 0.f, 0.f};
    z = __builtin_amdgcn_mfma_f32_16x16x32_bf16(a0, bq0, z, 0, 0, 0);
    st[0] = __builtin_amdgcn_mfma_f32_16x16x32_bf16(a1, bq1, z, 0, 0, 0);
    st[1] = f32x4{0.f, 0.f, 0.f, 0.f};
  }

  float m = -3.0e38f;
#pragma unroll
  for (int kt = 0; kt < 2; ++kt)
#pragma unroll
    for (int r = 0; r < 4; ++r) {
      int idx = kt * 16 + g * 4 + r;
      bool valid;
      if (local) {
        int rel = kstart + idx - qbase - fr;
        valid = (rel >= -8) && (rel <= 8);
      } else {
        valid = (idx < 8);
      }
      float s = valid ? st[kt][r] * 0.125f : -1.0e30f;
      st[kt][r] = s;
      m = fmaxf(m, s);
    }
  m = fmaxf(m, __shfl_xor(m, 16, 64));
  m = fmaxf(m, __shfl_xor(m, 32, 64));

  float lsum = 0.f;
#pragma unroll
  for (int kt = 0; kt < 2; ++kt)
#pragma unroll
    for (int r = 0; r < 4; ++r) {
      float e = __expf(st[kt][r] - m);
      st[kt][r] = e;
      lsum += e;
    }
  lsum += __shfl_xor(lsum, 16, 64);
  lsum += __shfl_xor(lsum, 32, 64);

  unsigned short* pl = smem + w * 640 + fr * 40 + g * 4;
#pragma unroll
  for (int kt = 0; kt < 2; ++kt) {
    uint2 pk;
    pk.x = (unsigned)f2b(st[kt][0]) | ((unsigned)f2b(st[kt][1]) << 16);
    pk.y = (unsigned)f2b(st[kt][2]) | ((unsigned)f2b(st[kt][3]) << 16);
    *(uint2*)(pl + kt * 16) = pk;
  }

  f32x4 oacc[4];
#pragma unroll
  for (int mf = 0; mf < 4; ++mf)
#pragma unroll
    for (int r = 0; r < 4; ++r) oacc[mf][r] = 0.f;

  const unsigned short* pr = smem + w * 640 + fr * 40 + g * 8;
  bf16x8 pf = *(const bf16x8*)(pr);
  long kb2 = local ? kstart : 0;
#pragma unroll
  for (int mf = 0; mf < 4; ++mf) {
    const unsigned short* vp =
        Vt + ((long)b * DD + hoff + mf * 16 + fr) * VSTR + kb2 + g * 8;
    bf16x8 vf = *(const bf16x8*)(vp);
    oacc[mf] = __builtin_amdgcn_mfma_f32_16x16x32_bf16(vf, pf, oacc[mf], 0, 0, 0);
  }

  float inv = 1.f / lsum;
  unsigned short* orow = comb + qrow * 2304 + brOff + hoff;
  float rsum = 0.f, rsq = 0.f;
#pragma unroll
  for (int mf = 0; mf < 4; ++mf) {
    float v0 = oacc[mf][0] * inv, v1 = oacc[mf][1] * inv;
    float v2 = oacc[mf][2] * inv, v3 = oacc[mf][3] * inv;
    rsum += v0 + v1 + v2 + v3;
    rsq  += v0 * v0 + v1 * v1 + v2 * v2 + v3 * v3;
    uint2 pk;
    pk.x = (unsigned)f2b(v0) | ((unsigned)f2b(v1) << 16);
    pk.y = (unsigned)f2b(v2) | ((unsigned)f2b(v3) << 16);
    *(uint2*)(orow + mf * 16 + g * 4) = pk;
  }
  rsum += __shfl_xor(rsum, 16, 64);
  rsum += __shfl_xor(rsum, 32, 64);
  rsq  += __shfl_xor(rsq, 16, 64);
  rsq  += __shfl_xor(rsq, 32, 64);
  if (lane < 16) {
    atomicAdd(&sumb[qrow], rsum);
    atomicAdd(&sqb[qrow], rsq);
  }
}

// ---------------- merged attention dispatch (z: 0=global 1=local 2=temporal)
__global__ __launch_bounds__(256) void attn_all(
    const unsigned short* __restrict__ QKV4,
    const unsigned short* __restrict__ KVg,
    const unsigned short* __restrict__ Vt,
    const unsigned short* __restrict__ Qt,
    const unsigned short* __restrict__ K8,
    const unsigned short* __restrict__ Vt8,
    const unsigned short* __restrict__ Vtl,
    unsigned short* __restrict__ comb,
    float* __restrict__ sumb, float* __restrict__ sqb) {
  __shared__ unsigned short smem[20736];
  int z = blockIdx.z;
  if (z == 0) {
    attn_flash_body(QKV4, KVg, Vt, comb, sumb, sqb, smem);
  } else if (z == 1) {
    attn_win_body(QKV4, nullptr, Vtl, comb, 768, sumb + NTOK, sqb + NTOK,
                  3072, 768, SS, true, smem);
  } else {
    attn_win_body(Qt, K8, Vt8, comb, 1536, sumb + 2 * NTOK, sqb + 2 * NTOK,
                  768, 0, 32, false, smem);
  }
}

// ---------------- launcher ---------------------------------------------------
extern "C" void kernel_launch(void* const* d_in, const int* in_sizes, int n_in,
                              void* d_out, int out_size, void* d_ws, size_t ws_size,
                              hipStream_t stream) {
  const float* x        = (const float*)d_in[0];
  const float* wgq      = (const float*)d_in[1];
  const float* wgk      = (const float*)d_in[2];
  const float* wgv      = (const float*)d_in[3];
  const float* wlq      = (const float*)d_in[4];
  const float* wlk      = (const float*)d_in[5];
  const float* wlv      = (const float*)d_in[6];
  const float* wtq      = (const float*)d_in[7];
  const float* wtk      = (const float*)d_in[8];
  const float* wtv      = (const float*)d_in[9];
  const float* w_out    = (const float*)d_in[10];
  const float* b_out    = (const float*)d_in[11];
  const float* w_gate   = (const float*)d_in[12];
  const float* b_gate   = (const float*)d_in[13];
  const float* w_sparse = (const float*)d_in[14];
  const float* b_sparse = (const float*)d_in[15];
  const float* g_gamma  = (const float*)d_in[16];
  const float* g_beta   = (const float*)d_in[17];
  const float* l_gamma  = (const float*)d_in[18];
  const float* l_beta   = (const float*)d_in[19];
  const float* t_gamma  = (const float*)d_in[20];
  const float* t_beta   = (const float*)d_in[21];
  float* outp = (float*)d_out;

  unsigned short* xb    = (unsigned short*)d_ws;
  unsigned short* xpb   = xb    + (long)NTOK * DD;
  unsigned short* WTx4  = xpb   + (long)NTOK * DD;        // [3072][768]
  unsigned short* WTkv  = WTx4  + (long)3072 * DD;        // [1536][768]
  unsigned short* WTqt  = WTkv  + (long)1536 * DD;        // [768][768]
  unsigned short* WTtkv = WTqt  + (long)DD * DD;          // [1536][768]
  unsigned short* WTo   = WTtkv + (long)1536 * DD;        // [768][2304] (gamma-folded)
  unsigned short* QKV4  = WTo   + (long)DD * 2304;        // [4096][3072]
  unsigned short* Qt    = QKV4  + (long)NTOK * 3072;      // [4096][768]
  unsigned short* KVg   = Qt    + (long)NTOK * DD;        // [896][1536]
  unsigned short* K8    = KVg   + (long)BB * KPAD * 1536; // [2][16][768]
  unsigned short* Vt8   = K8    + (long)BB * 16 * DD;     // [2][768][32]
  unsigned short* Vt    = Vt8   + (long)BB * DD * 32;     // [2][768][448]
  unsigned short* Vtl   = Vt    + (long)BB * DD * KPAD;   // [2][768][2048]
  unsigned short* comb  = Vtl   + (long)BB * DD * SS;     // [4096][2304] raw attn
  float* Cpart   = (float*)(comb + (long)NTOK * 2304);    // [3][4096][768]
  float* imp     = Cpart + 3L * NTOK * DD;
  float* partial = imp + NTOK;
  float* fw      = partial + 32 * DD;
  int*   sel     = (int*)(fw + 8);
  float* sumb    = (float*)(sel + 1024);                  // [3][4096]
  float* sqb     = sumb + 3 * NTOK;                       // [3][4096]
  float* Sbuf    = sqb + 3 * NTOK;                        // [3][768]
  float* Tbuf    = Sbuf + 3 * DD;                         // [3][768]

  hipMemsetAsync(sumb, 0, (size_t)(6 * NTOK + 6 * DD) * sizeof(float), stream);

  mega_pre<<<SS + 6912 + 32, 256, 0, stream>>>(
      x, w_sparse, b_sparse, xb, xpb, imp,
      wgq, wgk, wgv, wlq, wlk, wlv, wtq, wtk, wtv, w_out,
      g_gamma, l_gamma, t_gamma, g_beta, l_beta, t_beta,
      WTx4, WTkv, WTqt, WTtkv, WTo, Sbuf, Tbuf, partial);

  gemm_topk<<<976, 1024, 0, stream>>>(xb, WTx4, QKV4, xpb, WTqt, Qt, WTtkv,
                                      K8, Vt8, Vtl, imp, sel,
                                      partial, w_gate, b_gate, fw);
  gemm_kvg<<<84, 256, 0, stream>>>(xb, WTkv, KVg, sel, Vt);

  attn_all<<<dim3(32, BB * HH, 3), 256, 0, stream>>>(QKV4, KVg, Vt, Qt, K8, Vt8,
                                                     Vtl, comb, sumb, sqb);

  gemm_final_sk<<<dim3(6, 32, 3), 256, 0, stream>>>(comb, WTo, Cpart);
  reduce_out<<<NTOK * DD / 4 / 256, 256, 0, stream>>>(Cpart, b_out, sumb, sqb,
                                                      Sbuf, Tbuf, fw, outp);
}

// Round 19
// 173.788 us; speedup vs baseline: 1.0431x; 1.0431x over previous
//
#include <hip/hip_runtime.h>
#include <cstdint>

// Problem constants
constexpr int BB   = 2;
constexpr int SS   = 2048;
constexpr int DD   = 768;
constexpr int HH   = 12;
constexpr int NTOK = BB * SS;          // 4096
constexpr int KSEL = 409;              // int((1-0.8)*2048)
constexpr int KPAD = 448;              // 7 kv-tiles of 64
constexpr int NKT  = 7;                // kv tiles of 64 keys

typedef __bf16 bf16x8 __attribute__((ext_vector_type(8)));
typedef float  f32x4  __attribute__((ext_vector_type(4)));

__device__ __forceinline__ float b2f(unsigned short u) {
  return __uint_as_float(((unsigned)u) << 16);
}
__device__ __forceinline__ unsigned short f2b(float f) {
  unsigned u = __float_as_uint(f);
  u += 0x7fffu + ((u >> 16) & 1u);   // RNE
  return (unsigned short)(u >> 16);
}
__device__ __forceinline__ unsigned long long shfl_xor_u64(unsigned long long v, int m) {
  unsigned lo = (unsigned)v, hi = (unsigned)(v >> 32);
  lo = __shfl_xor(lo, m, 64);
  hi = __shfl_xor(hi, m, 64);
  return ((unsigned long long)hi << 32) | lo;
}

__device__ __forceinline__ void gload_lds16(const void* gsrc, void* ldst) {
  __builtin_amdgcn_global_load_lds(
      (__attribute__((address_space(1))) void*)(gsrc),
      (__attribute__((address_space(3))) void*)(ldst), 16, 0, 0);
}

// ------- mega_pre: prep_imp (2048) | weight transpose (6912) | gate1 (32) ---
__global__ __launch_bounds__(256) void mega_pre(
    const float* __restrict__ x, const float* __restrict__ wsp,
    const float* __restrict__ bsp,
    unsigned short* __restrict__ xb, unsigned short* __restrict__ xpb,
    float* __restrict__ imp,
    const float* w0, const float* w1, const float* w2, const float* w3,
    const float* w4, const float* w5, const float* w6, const float* w7,
    const float* w8, const float* w9,
    const float* __restrict__ gg, const float* __restrict__ lgam,
    const float* __restrict__ tg,
    const float* __restrict__ gb, const float* __restrict__ lbet,
    const float* __restrict__ tb,
    unsigned short* __restrict__ WTx4, unsigned short* __restrict__ WTkv,
    unsigned short* __restrict__ WTqt, unsigned short* __restrict__ WTtkv,
    unsigned short* __restrict__ WTo,
    float* __restrict__ Sbuf, float* __restrict__ Tbuf,
    float* __restrict__ partial) {
  __shared__ float tile[32][33];
  __shared__ float gsh[32], bsh[32];
  __shared__ float redS[8][32], redT[8][32];
  int id = blockIdx.x;
  int tid = threadIdx.x;

  if (id < SS) {
    int srow = id;
    const float* xr0 = x + (long)srow * DD;
    const float* xr1 = x + (long)(SS + srow) * DD;
    float acc0 = 0.f, acc1 = 0.f;
#pragma unroll
    for (int k = 0; k < 3; ++k) {
      int c = tid + k * 256;
      int j2 = c & ~1;
      float freq = __expf((float)j2 * -0.011992630692677323f);
      float ang = (float)srow * freq;
      float pe = (c & 1) ? __cosf(ang) : __sinf(ang);
      float w = wsp[c];
      float x0 = xr0[c], x1 = xr1[c];
      xb[(long)srow * DD + c]        = f2b(x0);
      xb[(long)(SS + srow) * DD + c] = f2b(x1);
      xpb[(long)srow * DD + c]        = f2b(x0 + pe);
      xpb[(long)(SS + srow) * DD + c] = f2b(x1 + pe);
      acc0 += x0 * w;
      acc1 += x1 * w;
    }
#pragma unroll
    for (int m = 1; m < 64; m <<= 1) {
      acc0 += __shfl_xor(acc0, m, 64);
      acc1 += __shfl_xor(acc1, m, 64);
    }
    __shared__ float red[8];
    int wv = tid >> 6, lane = tid & 63;
    if (lane == 0) { red[wv] = acc0; red[4 + wv] = acc1; }
    __syncthreads();
    if (tid == 0) {
      imp[srow]      = red[0] + red[1] + red[2] + red[3] + bsp[0];
      imp[SS + srow] = red[4] + red[5] + red[6] + red[7] + bsp[0];
    }
  } else if (id < SS + 6912) {
    int tidx = id - SS;
    int z, bx, by;
    if (tidx < 5184) { z = tidx / 576; int rem = tidx % 576; by = rem / 24; bx = rem % 24; }
    else             { z = 9; int rem = tidx - 5184; by = rem / 24; bx = rem % 24; }
    const float* srcs[10] = {w0, w1, w2, w3, w4, w5, w6, w7, w8, w9};
    const float* src = srcs[z];
    unsigned short* dst;
    int R = DD;
    switch (z) {
      case 0: dst = WTx4;                       break;
      case 1: dst = WTkv;                       break;
      case 2: dst = WTkv + (long)DD * DD;       break;
      case 3: dst = WTx4 + (long)DD * DD;       break;
      case 4: dst = WTx4 + (long)2 * DD * DD;   break;
      case 5: dst = WTx4 + (long)3 * DD * DD;   break;
      case 6: dst = WTqt;                       break;
      case 7: dst = WTtkv;                      break;
      case 8: dst = WTtkv + (long)DD * DD;      break;
      default: dst = WTo; R = 2304;             break;
    }
    int r0 = by * 32, c0 = bx * 32;
    int tx = tid & 31, ty = tid >> 5;
    for (int i = ty; i < 32; i += 8) tile[i][tx] = src[(long)(r0 + i) * DD + c0 + tx];
    if (z == 9 && ty == 0) {
      int kk = r0 + tx;                    // tile is single-branch (768 % 32 == 0)
      gsh[tx] = (kk < 768) ? gg[kk] : (kk < 1536) ? lgam[kk - 768] : tg[kk - 1536];
      bsh[tx] = (kk < 768) ? gb[kk] : (kk < 1536) ? lbet[kk - 768] : tb[kk - 1536];
    }
    __syncthreads();
    if (z == 9) {
      float gamv = gsh[tx];
      for (int i = ty; i < 32; i += 8)
        dst[(long)(c0 + i) * R + r0 + tx] = f2b(tile[tx][i] * gamv);
      float pS = 0.f, pT = 0.f;
      for (int i = ty; i < 32; i += 8) {
        float wv = tile[i][tx];
        pS += gsh[i] * wv;
        pT += bsh[i] * wv;
      }
      redS[ty][tx] = pS; redT[ty][tx] = pT;
      __syncthreads();
      if (ty == 0) {
        float s = 0.f, t2 = 0.f;
#pragma unroll
        for (int j = 0; j < 8; ++j) { s += redS[j][tx]; t2 += redT[j][tx]; }
        int br = r0 / 768;
        atomicAdd(&Sbuf[br * DD + c0 + tx], s);
        atomicAdd(&Tbuf[br * DD + c0 + tx], t2);
      }
    } else {
      for (int i = ty; i < 32; i += 8)
        dst[(long)(c0 + i) * R + r0 + tx] = f2b(tile[tx][i]);
    }
  } else {
    int rem = id - SS - 6912;            // 0..31
    int chunk = rem & 15, b = rem >> 4;
    for (int c = tid; c < DD; c += 256) {
      const float* xp = x + ((long)(b * SS + chunk * 128)) * DD + c;
      float acc = 0.f;
      for (int s2 = 0; s2 < 128; ++s2) acc += xp[(long)s2 * DD];
      partial[(long)(b * 16 + chunk) * DD + c] = acc;
    }
  }
}

// ------- fused (256 threads): sel-free GEMM (0..971) | topk (972..973) |
//         gate2 (974..975). LDS unioned at 32 KB.
__global__ __launch_bounds__(256) void gemm_topk(
    const unsigned short* __restrict__ xb,    const unsigned short* __restrict__ WTx4,
    unsigned short* __restrict__ QKV4,
    const unsigned short* __restrict__ xpb,   const unsigned short* __restrict__ WTqt,
    unsigned short* __restrict__ Qt,
    const unsigned short* __restrict__ WTtkv,
    unsigned short* __restrict__ K8, unsigned short* __restrict__ Vt8,
    unsigned short* __restrict__ Vtl,
    const float* __restrict__ imp, int* __restrict__ sel,
    const float* __restrict__ partial, const float* __restrict__ w_gate,
    const float* __restrict__ b_gate, float* __restrict__ fw) {
  __shared__ unsigned long long smem_u64[4096];   // 32 KB union
  int id = blockIdx.x;
  int tid = threadIdx.x;

  if (id < 972) {
    // ------------- GEMM tiles (regions 0: QKV4, 2: Qt, 3: T8) --------------
    unsigned short* AsB = (unsigned short*)smem_u64;   // [2][4096]
    unsigned short* BsB = AsB + 8192;
    constexpr int K = DD;
    const int lane = tid & 63;
    const int wv = tid >> 6;
    const int wr = wv >> 1, wc = wv & 1;

    const unsigned short* BT;
    int ntx, tile, region;
    if (id < 768) {
      region = 0; BT = WTx4; ntx = 24;
      int xcd = id & 7, idx = id >> 3;   // idx in [0,96)
      int r = (xcd >> 2) * 16 + (idx & 15);
      int c = (xcd & 3) * 6 + (idx >> 4);
      tile = r * 24 + c;
    } else {
      int e = id - 768;                  // 0..203
      if (e < 192) { region = 2; BT = WTqt;  ntx = 6;  tile = e; }
      else         { region = 3; BT = WTtkv; ntx = 12; tile = e - 192; }
    }
    const long rowBase = (long)(tile / ntx) * 128;
    const long colBase = (long)(tile % ntx) * 128;

    auto arow = [&](int r) -> const unsigned short* {
      long grow = rowBase + r;
      if (region == 0) return xb + grow * (long)K;
      if (region == 2) return xpb + grow * (long)K;
      if (grow < 16) {
        int bb2 = (int)grow >> 3, j = ((int)grow & 7) * 256;
        return xpb + ((long)bb2 * SS + j) * (long)K;
      }
      return xpb;   // T8 rows >=16 never stored
    };

    f32x4 acc[4][4];
#pragma unroll
    for (int i = 0; i < 4; ++i)
#pragma unroll
      for (int j = 0; j < 4; ++j)
#pragma unroll
        for (int r = 0; r < 4; ++r) acc[i][j][r] = 0.f;

    const int g0 = tid, g1 = tid + 256;
    const int r0 = g0 >> 2, k80 = (g0 & 3) ^ ((r0 >> 1) & 3);
    const int r1 = g1 >> 2, k81 = (g1 & 3) ^ ((r1 >> 1) & 3);
    const unsigned short* ga0 = arow(r0) + k80 * 8;
    const unsigned short* ga1 = arow(r1) + k81 * 8;
    const unsigned short* gb0 = BT + (colBase + r0) * (long)K + k80 * 8;
    const unsigned short* gb1 = BT + (colBase + r1) * (long)K + k81 * 8;

    const int k8 = lane >> 4;
    const int fr = lane & 15;
    int aoff[4], boff[4];
#pragma unroll
    for (int i = 0; i < 4; ++i) {
      int rowA = wr * 64 + i * 16 + fr;
      aoff[i] = (rowA * 4 + (k8 ^ ((rowA >> 1) & 3))) * 8;
      int rowB = wc * 64 + i * 16 + fr;
      boff[i] = (rowB * 4 + (k8 ^ ((rowB >> 1) & 3))) * 8;
    }

    auto stage = [&](int buf, int t) {
      int ko = t * 32;
      gload_lds16(ga0 + ko, &AsB[buf * 4096 + g0 * 8]);
      gload_lds16(ga1 + ko, &AsB[buf * 4096 + g1 * 8]);
      gload_lds16(gb0 + ko, &BsB[buf * 4096 + g0 * 8]);
      gload_lds16(gb1 + ko, &BsB[buf * 4096 + g1 * 8]);
    };

    constexpr int nk = K >> 5;   // 24
    stage(0, 0);
    __syncthreads();
    for (int t = 0; t < nk; ++t) {
      int cur = t & 1;
      if (t + 1 < nk) stage(cur ^ 1, t + 1);
      bf16x8 af[4], bfr[4];
#pragma unroll
      for (int i = 0; i < 4; ++i) af[i] = *(const bf16x8*)(&AsB[cur * 4096 + aoff[i]]);
#pragma unroll
      for (int i = 0; i < 4; ++i) bfr[i] = *(const bf16x8*)(&BsB[cur * 4096 + boff[i]]);
#pragma unroll
      for (int mi = 0; mi < 4; ++mi)
#pragma unroll
        for (int ni = 0; ni < 4; ++ni)
          acc[mi][ni] = __builtin_amdgcn_mfma_f32_16x16x32_bf16(af[mi], bfr[ni], acc[mi][ni], 0, 0, 0);
      __syncthreads();
    }

    int mode, vcol0 = 0, N = 0;
    unsigned short* C = nullptr;
    if (region == 0)      { mode = (colBase >= 2304) ? 1 : 0; C = QKV4; N = 3072;
                            vcol0 = (int)colBase - 2304; }
    else if (region == 2) { mode = 0; C = Qt; N = 768; }
    else                  { mode = (colBase >= 768) ? 4 : 3;
                            vcol0 = (int)colBase - 768; }

    const int orow0 = (lane >> 4) * 4;
    if (mode == 0) {
#pragma unroll
      for (int mi = 0; mi < 4; ++mi) {
        long gr = rowBase + wr * 64 + mi * 16 + orow0;
#pragma unroll
        for (int ni = 0; ni < 4; ++ni) {
          long gc = colBase + wc * 64 + ni * 16 + fr;
#pragma unroll
          for (int r = 0; r < 4; ++r)
            C[(gr + r) * (long)N + gc] = f2b(acc[mi][ni][r]);
        }
      }
    } else {
#pragma unroll
      for (int mi = 0; mi < 4; ++mi) {
        int lr = wr * 64 + mi * 16 + orow0;
        int grow = (int)rowBase + lr;
#pragma unroll
        for (int ni = 0; ni < 4; ++ni) {
          int lc = wc * 64 + ni * 16 + fr;
          uint2 pk;
          pk.x = (unsigned)f2b(acc[mi][ni][0]) | ((unsigned)f2b(acc[mi][ni][1]) << 16);
          pk.y = (unsigned)f2b(acc[mi][ni][2]) | ((unsigned)f2b(acc[mi][ni][3]) << 16);
          if (mode == 1) {         // QKV4 v_l -> Vtl[b][c][s]
            int bb2 = grow >> 11, s = grow & (SS - 1);
            *(uint2*)(Vtl + ((long)bb2 * DD + vcol0 + lc) * SS + s) = pk;
          } else if (mode == 3) {  // T8 k -> K8[b][16][768] rows 0..7 per b
            if (grow < 16) {
#pragma unroll
              for (int r = 0; r < 4; ++r) {
                int g2 = grow + r;
                K8[((long)(g2 >> 3) * 16 + (g2 & 7)) * DD + colBase + lc] =
                    f2b(acc[mi][ni][r]);
              }
            }
          } else {                 // mode 4: T8 v -> Vt8[b][c][32] j 0..7
            if (grow < 16) {
              *(uint2*)(Vt8 + ((long)(grow >> 3) * DD + vcol0 + lc) * 32 + (grow & 7)) = pk;
            }
          }
        }
      }
      if (mode == 4) {             // zero Vt8 j=8..31
#pragma unroll
        for (int e = 0; e < 6; ++e) {
          int id2 = tid + e * 256;
          int bb2 = id2 / 768, rem = id2 % 768;
          int c = rem / 6, ch = rem % 6;
          *(uint2*)(Vt8 + ((long)bb2 * DD + vcol0 + c) * 32 + 8 + ch * 4) = uint2{0u, 0u};
        }
      }
    }
  } else if (id < 974) {
    // -------- topk (256 threads): hybrid bitonic (value desc, index asc) ---
    // element i = s*256 + tid; j>=64 stages in LDS, j<=32 via shfl (partner
    // tid^j stays in-wave; direction (i&k2) computed per element).
    unsigned long long* keys = smem_u64;   // [2048]
    int b = id - 972;
    for (int i = tid; i < SS; i += 256) {
      float v = imp[b * SS + i];
      unsigned u = __float_as_uint(v);
      u = (u & 0x80000000u) ? ~u : (u | 0x80000000u);
      unsigned du = ~u;
      keys[i] = ((unsigned long long)du << 32) | (unsigned)i;
    }
    __syncthreads();
    for (int k2 = 2; k2 <= SS; k2 <<= 1) {
      for (int j = k2 >> 1; j >= 64; j >>= 1) {
        for (int i = tid; i < SS; i += 256) {
          int p = i ^ j;
          if (p > i) {
            unsigned long long a = keys[i], bb = keys[p];
            bool up = ((i & k2) == 0);
            if ((a > bb) == up) { keys[i] = bb; keys[p] = a; }
          }
        }
        __syncthreads();
      }
      unsigned long long kr[8];
      bool up_s[8];
#pragma unroll
      for (int s = 0; s < 8; ++s) {
        int i = s * 256 + tid;
        kr[s] = keys[i];
        up_s[s] = ((i & k2) == 0);
      }
      int j0 = (k2 >> 1) < 32 ? (k2 >> 1) : 32;
      for (int j = j0; j >= 1; j >>= 1) {
        bool low = ((tid & j) == 0);   // j<=32: bit lives in tid
#pragma unroll
        for (int s = 0; s < 8; ++s) {
          unsigned long long p = shfl_xor_u64(kr[s], j);
          kr[s] = ((low == up_s[s]) == (kr[s] < p)) ? kr[s] : p;
        }
      }
#pragma unroll
      for (int s = 0; s < 8; ++s) keys[s * 256 + tid] = kr[s];
      __syncthreads();
    }
    for (int i = tid; i < KSEL; i += 256) sel[b * KSEL + i] = (int)(keys[i] & 0xffffffffu);
  } else {
    // ------------- gate2 (256 threads) -------------------------------------
    float* meanbuf = (float*)smem_u64;          // [768]
    float* lg = meanbuf + DD;                   // [3]
    int b = id - 974;
    for (int c = tid; c < DD; c += 256) {
      float acc = 0.f;
      for (int p = 0; p < 16; ++p) acc += partial[(long)(b * 16 + p) * DD + c];
      meanbuf[c] = acc * (1.0f / (float)SS);
    }
    __syncthreads();
    if (tid < 3) {
      float acc = b_gate[tid];
      for (int d = 0; d < DD; ++d) acc += meanbuf[d] * w_gate[d * 3 + tid];
      lg[tid] = acc;
    }
    __syncthreads();
    if (tid == 0) {
      float mx = fmaxf(lg[0], fmaxf(lg[1], lg[2]));
      float e0 = expf(lg[0] - mx), e1 = expf(lg[1] - mx), e2 = expf(lg[2] - mx);
      float inv = 1.f / (e0 + e1 + e2);
      fw[b * 3 + 0] = e0 * inv; fw[b * 3 + 1] = e1 * inv; fw[b * 3 + 2] = e2 * inv;
    }
  }
}

// ------- KVg projection (84 tiles, needs sel): K half + transposed V --------
__global__ __launch_bounds__(256) void gemm_kvg(
    const unsigned short* __restrict__ xb, const unsigned short* __restrict__ WTkv,
    unsigned short* __restrict__ KVg, const int* __restrict__ sel,
    unsigned short* __restrict__ Vt) {
  __shared__ unsigned short AsB[2][4096];
  __shared__ unsigned short BsB[2][4096];
  constexpr int K = DD;
  const int tid = threadIdx.x;
  const int lane = tid & 63;
  const int wv = tid >> 6;
  const int wr = wv >> 1, wc = wv & 1;

  int tile = blockIdx.x;                 // 84 = 7 row-tiles x 12 col-tiles
  const long rowBase = (long)(tile / 12) * 128;
  const long colBase = (long)(tile % 12) * 128;

  auto arow = [&](int r) -> const unsigned short* {
    long grow = rowBase + r;
    int bb2 = (int)(grow / KPAD), j = (int)(grow % KPAD);
    int srow = (j < KSEL) ? sel[bb2 * KSEL + j] : 0;
    return xb + ((long)bb2 * SS + srow) * (long)K;
  };

  f32x4 acc[4][4];
#pragma unroll
  for (int i = 0; i < 4; ++i)
#pragma unroll
    for (int j = 0; j < 4; ++j)
#pragma unroll
      for (int r = 0; r < 4; ++r) acc[i][j][r] = 0.f;

  const int g0 = tid, g1 = tid + 256;
  const int r0 = g0 >> 2, k80 = (g0 & 3) ^ ((r0 >> 1) & 3);
  const int r1 = g1 >> 2, k81 = (g1 & 3) ^ ((r1 >> 1) & 3);
  const unsigned short* ga0 = arow(r0) + k80 * 8;
  const unsigned short* ga1 = arow(r1) + k81 * 8;
  const unsigned short* gb0 = WTkv + (colBase + r0) * (long)K + k80 * 8;
  const unsigned short* gb1 = WTkv + (colBase + r1) * (long)K + k81 * 8;

  const int k8 = lane >> 4;
  const int fr = lane & 15;
  int aoff[4], boff[4];
#pragma unroll
  for (int i = 0; i < 4; ++i) {
    int rowA = wr * 64 + i * 16 + fr;
    aoff[i] = (rowA * 4 + (k8 ^ ((rowA >> 1) & 3))) * 8;
    int rowB = wc * 64 + i * 16 + fr;
    boff[i] = (rowB * 4 + (k8 ^ ((rowB >> 1) & 3))) * 8;
  }

  auto stage = [&](int buf, int t) {
    int ko = t * 32;
    gload_lds16(ga0 + ko, &AsB[buf][g0 * 8]);
    gload_lds16(ga1 + ko, &AsB[buf][g1 * 8]);
    gload_lds16(gb0 + ko, &BsB[buf][g0 * 8]);
    gload_lds16(gb1 + ko, &BsB[buf][g1 * 8]);
  };

  constexpr int nk = K >> 5;   // 24
  stage(0, 0);
  __syncthreads();
  for (int t = 0; t < nk; ++t) {
    int cur = t & 1;
    if (t + 1 < nk) stage(cur ^ 1, t + 1);
    bf16x8 af[4], bfr[4];
#pragma unroll
    for (int i = 0; i < 4; ++i) af[i] = *(const bf16x8*)(&AsB[cur][aoff[i]]);
#pragma unroll
    for (int i = 0; i < 4; ++i) bfr[i] = *(const bf16x8*)(&BsB[cur][boff[i]]);
#pragma unroll
    for (int mi = 0; mi < 4; ++mi)
#pragma unroll
      for (int ni = 0; ni < 4; ++ni)
        acc[mi][ni] = __builtin_amdgcn_mfma_f32_16x16x32_bf16(af[mi], bfr[ni], acc[mi][ni], 0, 0, 0);
    __syncthreads();
  }

  const int orow0 = (lane >> 4) * 4;
  if (colBase < 768) {                   // K half -> KVg rows
#pragma unroll
    for (int mi = 0; mi < 4; ++mi) {
      long gr = rowBase + wr * 64 + mi * 16 + orow0;
#pragma unroll
      for (int ni = 0; ni < 4; ++ni) {
        long gc = colBase + wc * 64 + ni * 16 + fr;
#pragma unroll
        for (int r = 0; r < 4; ++r)
          KVg[(gr + r) * 1536L + gc] = f2b(acc[mi][ni][r]);
      }
    }
  } else {                               // V half -> Vt[b][c][j] transposed
    int vcol0 = (int)colBase - 768;
#pragma unroll
    for (int mi = 0; mi < 4; ++mi) {
      int grow = (int)rowBase + wr * 64 + mi * 16 + orow0;
      int bb2 = grow / KPAD, j = grow - bb2 * KPAD;
#pragma unroll
      for (int ni = 0; ni < 4; ++ni) {
        int lc = wc * 64 + ni * 16 + fr;
        uint2 pk;
        pk.x = (unsigned)f2b(acc[mi][ni][0]) | ((unsigned)f2b(acc[mi][ni][1]) << 16);
        pk.y = (unsigned)f2b(acc[mi][ni][2]) | ((unsigned)f2b(acc[mi][ni][3]) << 16);
        *(uint2*)(Vt + ((long)bb2 * DD + vcol0 + lc) * KPAD + j) = pk;
      }
    }
  }
}

// ---------------- final GEMM, split-K=3 into f32 partials -------------------
__global__ __launch_bounds__(256) void gemm_final_sk(const unsigned short* __restrict__ A,
                                                     const unsigned short* __restrict__ BT,
                                                     float* __restrict__ Cpart) {
  __shared__ unsigned short As[2][128 * 32];
  __shared__ unsigned short Bs[2][128 * 32];
  constexpr int N = 768, K = 2304, CK = 768;
  const int tid = threadIdx.x;
  const int lane = tid & 63;
  const int wv = tid >> 6;
  const int wr = wv >> 1, wc = wv & 1;
  const int z = blockIdx.z;

  int lin = blockIdx.y * gridDim.x + blockIdx.x;   // 192 blocks/plane
  int swz = (lin & 7) * 24 + (lin >> 3);
  const long rowBase = (long)(swz / 6) * 128;
  const long colBase = (long)(swz % 6) * 128;

  f32x4 acc[4][4];
#pragma unroll
  for (int i = 0; i < 4; ++i)
#pragma unroll
    for (int j = 0; j < 4; ++j)
#pragma unroll
      for (int r = 0; r < 4; ++r) acc[i][j][r] = 0.f;

  const int g0 = tid, g1 = tid + 256;
  const int r0 = g0 >> 2, k80 = (g0 & 3) ^ ((r0 >> 1) & 3);
  const int r1 = g1 >> 2, k81 = (g1 & 3) ^ ((r1 >> 1) & 3);
  const unsigned short* ga0 = A + (rowBase + r0) * (long)K + z * CK + k80 * 8;
  const unsigned short* ga1 = A + (rowBase + r1) * (long)K + z * CK + k81 * 8;
  const unsigned short* gb0 = BT + (colBase + r0) * (long)K + z * CK + k80 * 8;
  const unsigned short* gb1 = BT + (colBase + r1) * (long)K + z * CK + k81 * 8;

  const int k8 = lane >> 4;
  const int fr = lane & 15;
  int aoff[4], boff[4];
#pragma unroll
  for (int i = 0; i < 4; ++i) {
    int rowA = wr * 64 + i * 16 + fr;
    aoff[i] = (rowA * 4 + (k8 ^ ((rowA >> 1) & 3))) * 8;
    int rowB = wc * 64 + i * 16 + fr;
    boff[i] = (rowB * 4 + (k8 ^ ((rowB >> 1) & 3))) * 8;
  }

  auto stage = [&](int buf, int t) {
    int ko = t * 32;
    gload_lds16(ga0 + ko, &As[buf][g0 * 8]);
    gload_lds16(ga1 + ko, &As[buf][g1 * 8]);
    gload_lds16(gb0 + ko, &Bs[buf][g0 * 8]);
    gload_lds16(gb1 + ko, &Bs[buf][g1 * 8]);
  };

  constexpr int nk = CK >> 5;   // 24
  stage(0, 0);
  __syncthreads();
  for (int t = 0; t < nk; ++t) {
    int cur = t & 1;
    if (t + 1 < nk) stage(cur ^ 1, t + 1);
    bf16x8 af[4], bfr[4];
#pragma unroll
    for (int i = 0; i < 4; ++i) af[i] = *(const bf16x8*)(&As[cur][aoff[i]]);
#pragma unroll
    for (int i = 0; i < 4; ++i) bfr[i] = *(const bf16x8*)(&Bs[cur][boff[i]]);
#pragma unroll
    for (int mi = 0; mi < 4; ++mi)
#pragma unroll
      for (int ni = 0; ni < 4; ++ni)
        acc[mi][ni] = __builtin_amdgcn_mfma_f32_16x16x32_bf16(af[mi], bfr[ni], acc[mi][ni], 0, 0, 0);
    __syncthreads();
  }

  float* Cz = Cpart + (long)z * NTOK * DD;
  const int orow0 = (lane >> 4) * 4;
#pragma unroll
  for (int mi = 0; mi < 4; ++mi) {
    long gr = rowBase + wr * 64 + mi * 16 + orow0;
#pragma unroll
    for (int ni = 0; ni < 4; ++ni) {
      long gc = colBase + wc * 64 + ni * 16 + fr;
#pragma unroll
      for (int r = 0; r < 4; ++r)
        Cz[(gr + r) * (long)N + gc] = acc[mi][ni][r];
    }
  }
}

// ------- reduce partials, applying the folded-LN affine per branch ----------
__global__ __launch_bounds__(256) void reduce_out(const float* __restrict__ P,
                                                  const float* __restrict__ bias,
                                                  const float* __restrict__ sumb,
                                                  const float* __restrict__ sqb,
                                                  const float* __restrict__ Sbuf,
                                                  const float* __restrict__ Tbuf,
                                                  const float* __restrict__ fw,
                                                  float* __restrict__ out) {
  long i = (long)blockIdx.x * 256 + threadIdx.x;   // over NTOK*DD/4 f32x4
  int r = (int)(i / (DD / 4));
  int c4 = (int)(i % (DD / 4));
  int b = r >> 11;
  f32x4 o = *(const f32x4*)(bias + c4 * 4);
#pragma unroll
  for (int br = 0; br < 3; ++br) {
    float sum = sumb[br * NTOK + r];
    float sq  = sqb[br * NTOK + r];
    float mean = sum * (1.f / (float)DD);
    float var  = sq * (1.f / (float)DD) - mean * mean;
    float rs   = rsqrtf(var + 1e-5f);
    float gate = fw[b * 3 + br];
    f32x4 P4 = ((const f32x4*)(P + (long)br * NTOK * DD))[i];
    f32x4 S4 = *(const f32x4*)(Sbuf + br * DD + c4 * 4);
    f32x4 T4 = *(const f32x4*)(Tbuf + br * DD + c4 * 4);
#pragma unroll
    for (int e = 0; e < 4; ++e)
      o[e] += gate * (rs * (P4[e] - mean * S4[e]) + T4[e]);
  }
  ((f32x4*)out)[i] = o;
}

// ---------------- attention bodies (raw bf16 output + row stats) ------------
__device__ __forceinline__ void attn_flash_body(
    const unsigned short* __restrict__ QKV4,
    const unsigned short* __restrict__ KVg,
    const unsigned short* __restrict__ Vt,
    unsigned short* __restrict__ comb,
    float* __restrict__ sumb, float* __restrict__ sqb,
    unsigned short* smem) {
  unsigned short* Kl = smem;            // [2][64*64]
  unsigned short* Vl = smem + 8192;     // [2][64*64]
  unsigned short* Pl = smem + 16384;    // [4][16*68]
  int tid = threadIdx.x, w = tid >> 6, lane = tid & 63;
  int fr = lane & 15, g = lane >> 4;
  int b = blockIdx.y / HH, h = blockIdx.y % HH, hoff = h * 64;
  int qbase = blockIdx.x * 64 + w * 16;
  long qrow = (long)b * SS + qbase + fr;

  const unsigned short* qptr = QKV4 + qrow * 3072 + hoff + g * 8;
  bf16x8 bq0 = *(const bf16x8*)(qptr);
  bf16x8 bq1 = *(const bf16x8*)(qptr + 32);

  const int s0 = tid, s1 = tid + 256;
  const int r0 = s0 >> 3, c0 = (s0 & 7) ^ (r0 & 7);
  const int r1 = s1 >> 3, c1 = (s1 & 7) ^ (r1 & 7);
  const unsigned short* kg_b = KVg + (long)b * KPAD * 1536 + hoff;
  const unsigned short* vt_b = Vt + ((long)b * DD + hoff) * KPAD;

  auto stage = [&](int buf, int t0) {
    gload_lds16(kg_b + (long)(t0 * 64 + r0) * 1536 + c0 * 8, &Kl[buf * 4096 + s0 * 8]);
    gload_lds16(kg_b + (long)(t0 * 64 + r1) * 1536 + c1 * 8, &Kl[buf * 4096 + s1 * 8]);
    gload_lds16(vt_b + (long)r0 * KPAD + t0 * 64 + c0 * 8, &Vl[buf * 4096 + s0 * 8]);
    gload_lds16(vt_b + (long)r1 * KPAD + t0 * 64 + c1 * 8, &Vl[buf * 4096 + s1 * 8]);
  };

  f32x4 oacc[4];
#pragma unroll
  for (int mf = 0; mf < 4; ++mf)
#pragma unroll
    for (int r = 0; r < 4; ++r) oacc[mf][r] = 0.f;
  float m = -3.0e38f, l = 0.f;

  stage(0, 0);
  asm volatile("s_waitcnt vmcnt(0)" ::: "memory");
  __syncthreads();

  for (int t = 0; t < NKT; ++t) {
    int cur = t & 1;
    if (t + 1 < NKT) stage(cur ^ 1, t + 1);

    f32x4 st[4];
#pragma unroll
    for (int kt = 0; kt < 4; ++kt) {
      int row = kt * 16 + fr;
      bf16x8 a0 = *(const bf16x8*)(&Kl[cur * 4096 + (row * 8 + (g ^ (row & 7))) * 8]);
      bf16x8 a1 = *(const bf16x8*)(&Kl[cur * 4096 + (row * 8 + ((4 + g) ^ (row & 7))) * 8]);
      f32x4 z = {0.f, 0.f, 0.f, 0.f};
      z = __builtin_amdgcn_mfma_f32_16x16x32_bf16(a0, bq0, z, 0, 0, 0);
      st[kt] = __builtin_amdgcn_mfma_f32_16x16x32_bf16(a1, bq1, z, 0, 0, 0);
    }

    float tm = -3.0e38f;
#pragma unroll
    for (int kt = 0; kt < 4; ++kt)
#pragma unroll
      for (int r = 0; r < 4; ++r) {
        int key = t * 64 + kt * 16 + g * 4 + r;
        float s = (key < KSEL) ? st[kt][r] * 0.125f : -1.0e30f;
        st[kt][r] = s;
        tm = fmaxf(tm, s);
      }
    tm = fmaxf(tm, __shfl_xor(tm, 16, 64));
    tm = fmaxf(tm, __shfl_xor(tm, 32, 64));
    float newm = fmaxf(m, tm);
    float f = __expf(m - newm);
    float tsum = 0.f;
#pragma unroll
    for (int kt = 0; kt < 4; ++kt)
#pragma unroll
      for (int r = 0; r < 4; ++r) {
        float e = __expf(st[kt][r] - newm);
        st[kt][r] = e;
        tsum += e;
      }
    tsum += __shfl_xor(tsum, 16, 64);
    tsum += __shfl_xor(tsum, 32, 64);
    l = l * f + tsum;
    m = newm;
#pragma unroll
    for (int mf = 0; mf < 4; ++mf)
#pragma unroll
      for (int r = 0; r < 4; ++r) oacc[mf][r] *= f;

    unsigned short* pw = &Pl[w * 1088 + fr * 68 + g * 4];
#pragma unroll
    for (int kt = 0; kt < 4; ++kt) {
      uint2 pk;
      pk.x = (unsigned)f2b(st[kt][0]) | ((unsigned)f2b(st[kt][1]) << 16);
      pk.y = (unsigned)f2b(st[kt][2]) | ((unsigned)f2b(st[kt][3]) << 16);
      *(uint2*)(pw + kt * 16) = pk;
    }

    const unsigned short* prd = &Pl[w * 1088 + fr * 68];
#pragma unroll
    for (int ks2 = 0; ks2 < 2; ++ks2) {
      bf16x8 pf = *(const bf16x8*)(prd + ks2 * 32 + g * 8);
#pragma unroll
      for (int mf = 0; mf < 4; ++mf) {
        int vr = mf * 16 + fr;
        int vc = ks2 * 4 + g;
        bf16x8 vf = *(const bf16x8*)(&Vl[cur * 4096 + (vr * 8 + (vc ^ (vr & 7))) * 8]);
        oacc[mf] = __builtin_amdgcn_mfma_f32_16x16x32_bf16(vf, pf, oacc[mf], 0, 0, 0);
      }
    }

    asm volatile("s_waitcnt vmcnt(0)" ::: "memory");
    __syncthreads();
  }

  float inv = 1.f / l;
  unsigned short* orow = comb + qrow * 2304 + hoff;
  float rsum = 0.f, rsq = 0.f;
#pragma unroll
  for (int mf = 0; mf < 4; ++mf) {
    float v0 = oacc[mf][0] * inv, v1 = oacc[mf][1] * inv;
    float v2 = oacc[mf][2] * inv, v3 = oacc[mf][3] * inv;
    rsum += v0 + v1 + v2 + v3;
    rsq  += v0 * v0 + v1 * v1 + v2 * v2 + v3 * v3;
    uint2 pk;
    pk.x = (unsigned)f2b(v0) | ((unsigned)f2b(v1) << 16);
    pk.y = (unsigned)f2b(v2) | ((unsigned)f2b(v3) << 16);
    *(uint2*)(orow + mf * 16 + g * 4) = pk;
  }
  rsum += __shfl_xor(rsum, 16, 64);
  rsum += __shfl_xor(rsum, 32, 64);
  rsq  += __shfl_xor(rsq, 16, 64);
  rsq  += __shfl_xor(rsq, 32, 64);
  if (lane < 16) {
    atomicAdd(&sumb[qrow], rsum);
    atomicAdd(&sqb[qrow], rsq);
  }
}

__device__ __forceinline__ void attn_win_body(
    const unsigned short* __restrict__ QKV,
    const unsigned short* __restrict__ K8,
    const unsigned short* __restrict__ Vt,
    unsigned short* __restrict__ comb, int brOff,
    float* __restrict__ sumb, float* __restrict__ sqb,
    int LD, int QO, long VSTR, bool local,
    unsigned short* smem) {
  int tid = threadIdx.x, w = tid >> 6, lane = tid & 63;
  int fr = lane & 15, g = lane >> 4;
  int b = blockIdx.y / HH, h = blockIdx.y % HH, hoff = h * 64;
  int qbase = blockIdx.x * 64 + w * 16;
  long qrow = (long)b * SS + qbase + fr;

  const unsigned short* qptr = QKV + qrow * LD + QO + hoff + g * 8;
  bf16x8 bq0 = *(const bf16x8*)(qptr);
  bf16x8 bq1 = *(const bf16x8*)(qptr + 32);

  int kstart = qbase - 8;
  if (kstart < 0) kstart = 0;
  if (kstart > SS - 32) kstart = SS - 32;

  f32x4 st[2];
  if (local) {
#pragma unroll
    for (int kt = 0; kt < 2; ++kt) {
      const unsigned short* kp =
          QKV + ((long)b * SS + kstart + kt * 16 + fr) * LD + 1536 + hoff + g * 8;
      bf16x8 a0 = *(const bf16x8*)(kp);
      bf16x8 a1 = *(const bf16x8*)(kp + 32);
      f32x4 z = {0.f, 0.f, 0.f, 0.f};
      z = __builtin_amdgcn_mfma_f32_16x16x32_bf16(a0, bq0, z, 0, 0, 0);
      st[kt] = __builtin_amdgcn_mfma_f32_16x16x32_bf16(a1, bq1, z, 0, 0, 0);
    }
  } else {
    const unsigned short* kp = K8 + ((long)b * 16 + fr) * DD + hoff + g * 8;
    bf16x8 a0 = *(const bf16x8*)(kp);
    bf16x8 a1 = *(const bf16x8*)(kp + 32);
    f32x4 z = {0.f, 0.f, 0.f, 0.f};
    z = __builtin_amdgcn_mfma_f32_16x16x32_bf16(a0, bq0, z, 0, 0, 0);
    st[0] = __builtin_amdgcn_mfma_f32_16x16x32_bf16(a1, bq1, z, 0, 0, 0);
    st[1] = f32x4{0.f, 0.f, 0.f, 0.f};
  }

  float m = -3.0e38f;
#pragma unroll
  for (int kt = 0; kt < 2; ++kt)
#pragma unroll
    for (int r = 0; r < 4; ++r) {
      int idx = kt * 16 + g * 4 + r;
      bool valid;
      if (local) {
        int rel = kstart + idx - qbase - fr;
        valid = (rel >= -8) && (rel <= 8);
      } else {
        valid = (idx < 8);
      }
      float s = valid ? st[kt][r] * 0.125f : -1.0e30f;
      st[kt][r] = s;
      m = fmaxf(m, s);
    }
  m = fmaxf(m, __shfl_xor(m, 16, 64));
  m = fmaxf(m, __shfl_xor(m, 32, 64));

  float lsum = 0.f;
#pragma unroll
  for (int kt = 0; kt < 2; ++kt)
#pragma unroll
    for (int r = 0; r < 4; ++r) {
      float e = __expf(st[kt][r] - m);
      st[kt][r] = e;
      lsum += e;
    }
  lsum += __shfl_xor(lsum, 16, 64);
  lsum += __shfl_xor(lsum, 32, 64);

  unsigned short* pl = smem + w * 640 + fr * 40 + g * 4;
#pragma unroll
  for (int kt = 0; kt < 2; ++kt) {
    uint2 pk;
    pk.x = (unsigned)f2b(st[kt][0]) | ((unsigned)f2b(st[kt][1]) << 16);
    pk.y = (unsigned)f2b(st[kt][2]) | ((unsigned)f2b(st[kt][3]) << 16);
    *(uint2*)(pl + kt * 16) = pk;
  }

  f32x4 oacc[4];
#pragma unroll
  for (int mf = 0; mf < 4; ++mf)
#pragma unroll
    for (int r = 0; r < 4; ++r) oacc[mf][r] = 0.f;

  const unsigned short* pr = smem + w * 640 + fr * 40 + g * 8;
  bf16x8 pf = *(const bf16x8*)(pr);
  long kb2 = local ? kstart : 0;
#pragma unroll
  for (int mf = 0; mf < 4; ++mf) {
    const unsigned short* vp =
        Vt + ((long)b * DD + hoff + mf * 16 + fr) * VSTR + kb2 + g * 8;
    bf16x8 vf = *(const bf16x8*)(vp);
    oacc[mf] = __builtin_amdgcn_mfma_f32_16x16x32_bf16(vf, pf, oacc[mf], 0, 0, 0);
  }

  float inv = 1.f / lsum;
  unsigned short* orow = comb + qrow * 2304 + brOff + hoff;
  float rsum = 0.f, rsq = 0.f;
#pragma unroll
  for (int mf = 0; mf < 4; ++mf) {
    float v0 = oacc[mf][0] * inv, v1 = oacc[mf][1] * inv;
    float v2 = oacc[mf][2] * inv, v3 = oacc[mf][3] * inv;
    rsum += v0 + v1 + v2 + v3;
    rsq  += v0 * v0 + v1 * v1 + v2 * v2 + v3 * v3;
    uint2 pk;
    pk.x = (unsigned)f2b(v0) | ((unsigned)f2b(v1) << 16);
    pk.y = (unsigned)f2b(v2) | ((unsigned)f2b(v3) << 16);
    *(uint2*)(orow + mf * 16 + g * 4) = pk;
  }
  rsum += __shfl_xor(rsum, 16, 64);
  rsum += __shfl_xor(rsum, 32, 64);
  rsq  += __shfl_xor(rsq, 16, 64);
  rsq  += __shfl_xor(rsq, 32, 64);
  if (lane < 16) {
    atomicAdd(&sumb[qrow], rsum);
    atomicAdd(&sqb[qrow], rsq);
  }
}

// ---------------- merged attention dispatch (z: 0=global 1=local 2=temporal)
__global__ __launch_bounds__(256) void attn_all(
    const unsigned short* __restrict__ QKV4,
    const unsigned short* __restrict__ KVg,
    const unsigned short* __restrict__ Vt,
    const unsigned short* __restrict__ Qt,
    const unsigned short* __restrict__ K8,
    const unsigned short* __restrict__ Vt8,
    const unsigned short* __restrict__ Vtl,
    unsigned short* __restrict__ comb,
    float* __restrict__ sumb, float* __restrict__ sqb) {
  __shared__ unsigned short smem[20736];
  int z = blockIdx.z;
  if (z == 0) {
    attn_flash_body(QKV4, KVg, Vt, comb, sumb, sqb, smem);
  } else if (z == 1) {
    attn_win_body(QKV4, nullptr, Vtl, comb, 768, sumb + NTOK, sqb + NTOK,
                  3072, 768, SS, true, smem);
  } else {
    attn_win_body(Qt, K8, Vt8, comb, 1536, sumb + 2 * NTOK, sqb + 2 * NTOK,
                  768, 0, 32, false, smem);
  }
}

// ---------------- launcher ---------------------------------------------------
extern "C" void kernel_launch(void* const* d_in, const int* in_sizes, int n_in,
                              void* d_out, int out_size, void* d_ws, size_t ws_size,
                              hipStream_t stream) {
  const float* x        = (const float*)d_in[0];
  const float* wgq      = (const float*)d_in[1];
  const float* wgk      = (const float*)d_in[2];
  const float* wgv      = (const float*)d_in[3];
  const float* wlq      = (const float*)d_in[4];
  const float* wlk      = (const float*)d_in[5];
  const float* wlv      = (const float*)d_in[6];
  const float* wtq      = (const float*)d_in[7];
  const float* wtk      = (const float*)d_in[8];
  const float* wtv      = (const float*)d_in[9];
  const float* w_out    = (const float*)d_in[10];
  const float* b_out    = (const float*)d_in[11];
  const float* w_gate   = (const float*)d_in[12];
  const float* b_gate   = (const float*)d_in[13];
  const float* w_sparse = (const float*)d_in[14];
  const float* b_sparse = (const float*)d_in[15];
  const float* g_gamma  = (const float*)d_in[16];
  const float* g_beta   = (const float*)d_in[17];
  const float* l_gamma  = (const float*)d_in[18];
  const float* l_beta   = (const float*)d_in[19];
  const float* t_gamma  = (const float*)d_in[20];
  const float* t_beta   = (const float*)d_in[21];
  float* outp = (float*)d_out;

  unsigned short* xb    = (unsigned short*)d_ws;
  unsigned short* xpb   = xb    + (long)NTOK * DD;
  unsigned short* WTx4  = xpb   + (long)NTOK * DD;        // [3072][768]
  unsigned short* WTkv  = WTx4  + (long)3072 * DD;        // [1536][768]
  unsigned short* WTqt  = WTkv  + (long)1536 * DD;        // [768][768]
  unsigned short* WTtkv = WTqt  + (long)DD * DD;          // [1536][768]
  unsigned short* WTo   = WTtkv + (long)1536 * DD;        // [768][2304] (gamma-folded)
  unsigned short* QKV4  = WTo   + (long)DD * 2304;        // [4096][3072]
  unsigned short* Qt    = QKV4  + (long)NTOK * 3072;      // [4096][768]
  unsigned short* KVg   = Qt    + (long)NTOK * DD;        // [896][1536]
  unsigned short* K8    = KVg   + (long)BB * KPAD * 1536; // [2][16][768]
  unsigned short* Vt8   = K8    + (long)BB * 16 * DD;     // [2][768][32]
  unsigned short* Vt    = Vt8   + (long)BB * DD * 32;     // [2][768][448]
  unsigned short* Vtl   = Vt    + (long)BB * DD * KPAD;   // [2][768][2048]
  unsigned short* comb  = Vtl   + (long)BB * DD * SS;     // [4096][2304] raw attn
  float* Cpart   = (float*)(comb + (long)NTOK * 2304);    // [3][4096][768]
  float* imp     = Cpart + 3L * NTOK * DD;
  float* partial = imp + NTOK;
  float* fw      = partial + 32 * DD;
  int*   sel     = (int*)(fw + 8);
  float* sumb    = (float*)(sel + 1024);                  // [3][4096]
  float* sqb     = sumb + 3 * NTOK;                       // [3][4096]
  float* Sbuf    = sqb + 3 * NTOK;                        // [3][768]
  float* Tbuf    = Sbuf + 3 * DD;                         // [3][768]

  hipMemsetAsync(sumb, 0, (size_t)(6 * NTOK + 6 * DD) * sizeof(float), stream);

  mega_pre<<<SS + 6912 + 32, 256, 0, stream>>>(
      x, w_sparse, b_sparse, xb, xpb, imp,
      wgq, wgk, wgv, wlq, wlk, wlv, wtq, wtk, wtv, w_out,
      g_gamma, l_gamma, t_gamma, g_beta, l_beta, t_beta,
      WTx4, WTkv, WTqt, WTtkv, WTo, Sbuf, Tbuf, partial);

  gemm_topk<<<976, 256, 0, stream>>>(xb, WTx4, QKV4, xpb, WTqt, Qt, WTtkv,
                                     K8, Vt8, Vtl, imp, sel,
                                     partial, w_gate, b_gate, fw);
  gemm_kvg<<<84, 256, 0, stream>>>(xb, WTkv, KVg, sel, Vt);

  attn_all<<<dim3(32, BB * HH, 3), 256, 0, stream>>>(QKV4, KVg, Vt, Qt, K8, Vt8,
                                                     Vtl, comb, sumb, sqb);

  gemm_final_sk<<<dim3(6, 32, 3), 256, 0, stream>>>(comb, WTo, Cpart);
  reduce_out<<<NTOK * DD / 4 / 256, 256, 0, stream>>>(Cpart, b_out, sumb, sqb,
                                                      Sbuf, Tbuf, fw, outp);
}

// Round 20
// 172.463 us; speedup vs baseline: 1.0511x; 1.0077x over previous
//
#include <hip/hip_runtime.h>
#include <cstdint>

// Problem constants
constexpr int BB   = 2;
constexpr int SS   = 2048;
constexpr int DD   = 768;
constexpr int HH   = 12;
constexpr int NTOK = BB * SS;          // 4096
constexpr int KSEL = 409;              // int((1-0.8)*2048)
constexpr int KPAD = 448;              // 7 kv-tiles of 64
constexpr int NKT  = 7;                // kv tiles of 64 keys

typedef __bf16 bf16x8 __attribute__((ext_vector_type(8)));
typedef float  f32x4  __attribute__((ext_vector_type(4)));

__device__ __forceinline__ float b2f(unsigned short u) {
  return __uint_as_float(((unsigned)u) << 16);
}
__device__ __forceinline__ unsigned short f2b(float f) {
  unsigned u = __float_as_uint(f);
  u += 0x7fffu + ((u >> 16) & 1u);   // RNE
  return (unsigned short)(u >> 16);
}

__device__ __forceinline__ void gload_lds16(const void* gsrc, void* ldst) {
  __builtin_amdgcn_global_load_lds(
      (__attribute__((address_space(1))) void*)(gsrc),
      (__attribute__((address_space(3))) void*)(ldst), 16, 0, 0);
}

// ------- mega_pre: prep_imp (2048) | weight transpose (6912) | gate1 (32) ---
__global__ __launch_bounds__(256) void mega_pre(
    const float* __restrict__ x, const float* __restrict__ wsp,
    const float* __restrict__ bsp,
    unsigned short* __restrict__ xb, unsigned short* __restrict__ xpb,
    float* __restrict__ imp,
    const float* w0, const float* w1, const float* w2, const float* w3,
    const float* w4, const float* w5, const float* w6, const float* w7,
    const float* w8, const float* w9,
    const float* __restrict__ gg, const float* __restrict__ lgam,
    const float* __restrict__ tg,
    const float* __restrict__ gb, const float* __restrict__ lbet,
    const float* __restrict__ tb,
    unsigned short* __restrict__ WTx4, unsigned short* __restrict__ WTkv,
    unsigned short* __restrict__ WTqt, unsigned short* __restrict__ WTtkv,
    unsigned short* __restrict__ WTo,
    float* __restrict__ Sbuf, float* __restrict__ Tbuf,
    float* __restrict__ partial) {
  __shared__ float tile[32][33];
  __shared__ float gsh[32], bsh[32];
  __shared__ float redS[8][32], redT[8][32];
  int id = blockIdx.x;
  int tid = threadIdx.x;

  if (id < SS) {
    int srow = id;
    const float* xr0 = x + (long)srow * DD;
    const float* xr1 = x + (long)(SS + srow) * DD;
    float acc0 = 0.f, acc1 = 0.f;
#pragma unroll
    for (int k = 0; k < 3; ++k) {
      int c = tid + k * 256;
      int j2 = c & ~1;
      float freq = __expf((float)j2 * -0.011992630692677323f);
      float ang = (float)srow * freq;
      float pe = (c & 1) ? __cosf(ang) : __sinf(ang);
      float w = wsp[c];
      float x0 = xr0[c], x1 = xr1[c];
      xb[(long)srow * DD + c]        = f2b(x0);
      xb[(long)(SS + srow) * DD + c] = f2b(x1);
      xpb[(long)srow * DD + c]        = f2b(x0 + pe);
      xpb[(long)(SS + srow) * DD + c] = f2b(x1 + pe);
      acc0 += x0 * w;
      acc1 += x1 * w;
    }
#pragma unroll
    for (int m = 1; m < 64; m <<= 1) {
      acc0 += __shfl_xor(acc0, m, 64);
      acc1 += __shfl_xor(acc1, m, 64);
    }
    __shared__ float red[8];
    int wv = tid >> 6, lane = tid & 63;
    if (lane == 0) { red[wv] = acc0; red[4 + wv] = acc1; }
    __syncthreads();
    if (tid == 0) {
      imp[srow]      = red[0] + red[1] + red[2] + red[3] + bsp[0];
      imp[SS + srow] = red[4] + red[5] + red[6] + red[7] + bsp[0];
    }
  } else if (id < SS + 6912) {
    int tidx = id - SS;
    int z, bx, by;
    if (tidx < 5184) { z = tidx / 576; int rem = tidx % 576; by = rem / 24; bx = rem % 24; }
    else             { z = 9; int rem = tidx - 5184; by = rem / 24; bx = rem % 24; }
    const float* srcs[10] = {w0, w1, w2, w3, w4, w5, w6, w7, w8, w9};
    const float* src = srcs[z];
    unsigned short* dst;
    int R = DD;
    switch (z) {
      case 0: dst = WTx4;                       break;
      case 1: dst = WTkv;                       break;
      case 2: dst = WTkv + (long)DD * DD;       break;
      case 3: dst = WTx4 + (long)DD * DD;       break;
      case 4: dst = WTx4 + (long)2 * DD * DD;   break;
      case 5: dst = WTx4 + (long)3 * DD * DD;   break;
      case 6: dst = WTqt;                       break;
      case 7: dst = WTtkv;                      break;
      case 8: dst = WTtkv + (long)DD * DD;      break;
      default: dst = WTo; R = 2304;             break;
    }
    int r0 = by * 32, c0 = bx * 32;
    int tx = tid & 31, ty = tid >> 5;
    for (int i = ty; i < 32; i += 8) tile[i][tx] = src[(long)(r0 + i) * DD + c0 + tx];
    if (z == 9 && ty == 0) {
      int kk = r0 + tx;                    // tile is single-branch (768 % 32 == 0)
      gsh[tx] = (kk < 768) ? gg[kk] : (kk < 1536) ? lgam[kk - 768] : tg[kk - 1536];
      bsh[tx] = (kk < 768) ? gb[kk] : (kk < 1536) ? lbet[kk - 768] : tb[kk - 1536];
    }
    __syncthreads();
    if (z == 9) {
      float gamv = gsh[tx];
      for (int i = ty; i < 32; i += 8)
        dst[(long)(c0 + i) * R + r0 + tx] = f2b(tile[tx][i] * gamv);
      float pS = 0.f, pT = 0.f;
      for (int i = ty; i < 32; i += 8) {
        float wv = tile[i][tx];
        pS += gsh[i] * wv;
        pT += bsh[i] * wv;
      }
      redS[ty][tx] = pS; redT[ty][tx] = pT;
      __syncthreads();
      if (ty == 0) {
        float s = 0.f, t2 = 0.f;
#pragma unroll
        for (int j = 0; j < 8; ++j) { s += redS[j][tx]; t2 += redT[j][tx]; }
        int br = r0 / 768;
        atomicAdd(&Sbuf[br * DD + c0 + tx], s);
        atomicAdd(&Tbuf[br * DD + c0 + tx], t2);
      }
    } else {
      for (int i = ty; i < 32; i += 8)
        dst[(long)(c0 + i) * R + r0 + tx] = f2b(tile[tx][i]);
    }
  } else {
    int rem = id - SS - 6912;            // 0..31
    int chunk = rem & 15, b = rem >> 4;
    for (int c = tid; c < DD; c += 256) {
      const float* xp = x + ((long)(b * SS + chunk * 128)) * DD + c;
      float acc = 0.f;
      for (int s2 = 0; s2 < 128; ++s2) acc += xp[(long)s2 * DD];
      partial[(long)(b * 16 + chunk) * DD + c] = acc;
    }
  }
}

// ------- topk via exact 64-bit radix SELECT (blocks 0..1) + gate2 (2..3) ----
// Keys (~u)<<32 | idx are unique; T = KSEL-th smallest key; sel = {key <= T}.
// Set equality with sorted top-k (value desc, index asc); order irrelevant
// downstream (softmax over the set; mask tests j < KSEL only).
__global__ __launch_bounds__(1024) void topk_gate2(
    const float* __restrict__ imp, int* __restrict__ sel,
    const float* __restrict__ partial, const float* __restrict__ w_gate,
    const float* __restrict__ b_gate, float* __restrict__ fw) {
  int tid = threadIdx.x;
  if (blockIdx.x < 2) {
    __shared__ unsigned long long keybuf[SS];
    __shared__ unsigned bins[256];
    __shared__ unsigned long long prefix_s;
    __shared__ unsigned long long Tsh;
    __shared__ int need_s, done_s;
    __shared__ unsigned cnt;
    int b = blockIdx.x;
    for (int i = tid; i < SS; i += 1024) {
      float v = imp[b * SS + i];
      unsigned u = __float_as_uint(v);
      u = (u & 0x80000000u) ? ~u : (u | 0x80000000u);   // ascending map
      unsigned du = ~u;                                  // descending
      keybuf[i] = ((unsigned long long)du << 32) | (unsigned)i;
    }
    if (tid == 0) { prefix_s = 0ULL; need_s = KSEL; done_s = 0; cnt = 0; }
    __syncthreads();

    for (int shift = 56; shift >= 0; shift -= 8) {
      unsigned long long himask = (shift == 56) ? 0ULL : (~0ULL << (shift + 8));
      if (tid < 256) bins[tid] = 0;
      __syncthreads();
      for (int i = tid; i < SS; i += 1024) {
        unsigned long long k = keybuf[i];
        if ((k & himask) == prefix_s)
          atomicAdd(&bins[(unsigned)((k >> shift) & 255ULL)], 1u);
      }
      __syncthreads();
      if (tid == 0) {
        unsigned cum = 0;
        int d = 0;
        for (; d < 255; ++d) {
          if (cum + bins[d] >= (unsigned)need_s) break;
          cum += bins[d];
        }
        prefix_s |= ((unsigned long long)(unsigned)d) << shift;
        need_s -= (int)cum;
        done_s = (bins[d] == 1 || shift == 0) ? 1 : 0;
      }
      __syncthreads();
      if (done_s) {
        unsigned long long smask = ~0ULL << shift;
        for (int i = tid; i < SS; i += 1024) {
          unsigned long long k = keybuf[i];
          if ((k & smask) == prefix_s) Tsh = k;   // exactly one match
        }
        __syncthreads();
        break;
      }
    }

    unsigned long long T = Tsh;
    for (int i = tid; i < SS; i += 1024) {
      if (keybuf[i] <= T) {
        unsigned p = atomicAdd(&cnt, 1u);
        sel[b * KSEL + p] = (int)(keybuf[i] & 0xffffffffu);
      }
    }
  } else {
    __shared__ float meanbuf[DD];
    __shared__ float lg[3];
    int b = blockIdx.x - 2;
    if (tid < DD) {
      float acc = 0.f;
      for (int p = 0; p < 16; ++p) acc += partial[(long)(b * 16 + p) * DD + tid];
      meanbuf[tid] = acc * (1.0f / (float)SS);
    }
    __syncthreads();
    if (tid < 3) {
      float acc = b_gate[tid];
      for (int d = 0; d < DD; ++d) acc += meanbuf[d] * w_gate[d * 3 + tid];
      lg[tid] = acc;
    }
    __syncthreads();
    if (tid == 0) {
      float mx = fmaxf(lg[0], fmaxf(lg[1], lg[2]));
      float e0 = expf(lg[0] - mx), e1 = expf(lg[1] - mx), e2 = expf(lg[2] - mx);
      float inv = 1.f / (e0 + e1 + e2);
      fw[b * 3 + 0] = e0 * inv; fw[b * 3 + 1] = e1 * inv; fw[b * 3 + 2] = e2 * inv;
    }
  }
}

// ---------------- fused projection GEMMs (all K=768, 128x128 tiles) ---------
__global__ __launch_bounds__(256) void gemm_multi(
    const unsigned short* __restrict__ xb,    const unsigned short* __restrict__ WTx4,
    unsigned short* __restrict__ QKV4,
    const unsigned short* __restrict__ WTkv,  unsigned short* __restrict__ KVg,
    const unsigned short* __restrict__ xpb,   const unsigned short* __restrict__ WTqt,
    unsigned short* __restrict__ Qt,
    const unsigned short* __restrict__ WTtkv,
    const int* __restrict__ sel,
    unsigned short* __restrict__ K8, unsigned short* __restrict__ Vt8,
    unsigned short* __restrict__ Vt, unsigned short* __restrict__ Vtl) {
  __shared__ unsigned short AsB[2][4096];
  __shared__ unsigned short BsB[2][4096];
  constexpr int K = DD;
  const int tid = threadIdx.x;
  const int lane = tid & 63;
  const int wv = tid >> 6;
  const int wr = wv >> 1, wc = wv & 1;

  int lin = blockIdx.x;
  int xcd = lin & 7, idx = lin >> 3;     // idx in [0,132)
  const unsigned short* BT;
  int ntx, tile, region;
  if (idx < 96) {
    region = 0; BT = WTx4; ntx = 24;
    int r = (xcd >> 2) * 16 + (idx & 15);
    int c = (xcd & 3) * 6 + (idx >> 4);
    tile = r * 24 + c;
  } else {
    int e = xcd * 36 + (idx - 96);       // 0..287
    if (e < 84)       { region = 1; BT = WTkv;  ntx = 12; tile = e; }
    else if (e < 276) { region = 2; BT = WTqt;  ntx = 6;  tile = e - 84; }
    else              { region = 3; BT = WTtkv; ntx = 12; tile = e - 276; }
  }
  const long rowBase = (long)(tile / ntx) * 128;
  const long colBase = (long)(tile % ntx) * 128;

  auto arow = [&](int r) -> const unsigned short* {
    long grow = rowBase + r;
    if (region == 0) return xb + grow * (long)K;
    if (region == 2) return xpb + grow * (long)K;
    if (region == 1) {
      int bb2 = (int)(grow / KPAD), j = (int)(grow % KPAD);
      int srow = (j < KSEL) ? sel[bb2 * KSEL + j] : 0;
      return xb + ((long)bb2 * SS + srow) * (long)K;
    }
    if (grow < 16) {
      int bb2 = (int)grow >> 3, j = ((int)grow & 7) * 256;
      return xpb + ((long)bb2 * SS + j) * (long)K;
    }
    return xpb;
  };

  f32x4 acc[4][4];
#pragma unroll
  for (int i = 0; i < 4; ++i)
#pragma unroll
    for (int j = 0; j < 4; ++j)
#pragma unroll
      for (int r = 0; r < 4; ++r) acc[i][j][r] = 0.f;

  const int g0 = tid, g1 = tid + 256;
  const int r0 = g0 >> 2, k80 = (g0 & 3) ^ ((r0 >> 1) & 3);
  const int r1 = g1 >> 2, k81 = (g1 & 3) ^ ((r1 >> 1) & 3);
  const unsigned short* ga0 = arow(r0) + k80 * 8;
  const unsigned short* ga1 = arow(r1) + k81 * 8;
  const unsigned short* gb0 = BT + (colBase + r0) * (long)K + k80 * 8;
  const unsigned short* gb1 = BT + (colBase + r1) * (long)K + k81 * 8;

  const int k8 = lane >> 4;
  const int fr = lane & 15;
  int aoff[4], boff[4];
#pragma unroll
  for (int i = 0; i < 4; ++i) {
    int rowA = wr * 64 + i * 16 + fr;
    aoff[i] = (rowA * 4 + (k8 ^ ((rowA >> 1) & 3))) * 8;
    int rowB = wc * 64 + i * 16 + fr;
    boff[i] = (rowB * 4 + (k8 ^ ((rowB >> 1) & 3))) * 8;
  }

  auto stage = [&](int buf, int t) {
    int ko = t * 32;
    gload_lds16(ga0 + ko, &AsB[buf][g0 * 8]);
    gload_lds16(ga1 + ko, &AsB[buf][g1 * 8]);
    gload_lds16(gb0 + ko, &BsB[buf][g0 * 8]);
    gload_lds16(gb1 + ko, &BsB[buf][g1 * 8]);
  };

  constexpr int nk = K >> 5;   // 24
  stage(0, 0);
  __syncthreads();
  for (int t = 0; t < nk; ++t) {
    int cur = t & 1;
    if (t + 1 < nk) stage(cur ^ 1, t + 1);
    bf16x8 af[4], bfr[4];
#pragma unroll
    for (int i = 0; i < 4; ++i) af[i] = *(const bf16x8*)(&AsB[cur][aoff[i]]);
#pragma unroll
    for (int i = 0; i < 4; ++i) bfr[i] = *(const bf16x8*)(&BsB[cur][boff[i]]);
#pragma unroll
    for (int mi = 0; mi < 4; ++mi)
#pragma unroll
      for (int ni = 0; ni < 4; ++ni)
        acc[mi][ni] = __builtin_amdgcn_mfma_f32_16x16x32_bf16(af[mi], bfr[ni], acc[mi][ni], 0, 0, 0);
    __syncthreads();
  }

  // epilogue
  int mode, vcol0 = 0, N = 0;
  unsigned short* C = nullptr;
  if (region == 0)      { mode = (colBase >= 2304) ? 1 : 0; C = QKV4; N = 3072;
                          vcol0 = (int)colBase - 2304; }
  else if (region == 1) { mode = (colBase >= 768) ? 2 : 0;  C = KVg;  N = 1536;
                          vcol0 = (int)colBase - 768; }
  else if (region == 2) { mode = 0; C = Qt; N = 768; }
  else                  { mode = (colBase >= 768) ? 4 : 3;
                          vcol0 = (int)colBase - 768; }

  const int orow0 = (lane >> 4) * 4;
  if (mode == 0) {
#pragma unroll
    for (int mi = 0; mi < 4; ++mi) {
      long gr = rowBase + wr * 64 + mi * 16 + orow0;
#pragma unroll
      for (int ni = 0; ni < 4; ++ni) {
        long gc = colBase + wc * 64 + ni * 16 + fr;
#pragma unroll
        for (int r = 0; r < 4; ++r)
          C[(gr + r) * (long)N + gc] = f2b(acc[mi][ni][r]);
      }
    }
  } else {
#pragma unroll
    for (int mi = 0; mi < 4; ++mi) {
      int lr = wr * 64 + mi * 16 + orow0;
      int grow = (int)rowBase + lr;
#pragma unroll
      for (int ni = 0; ni < 4; ++ni) {
        int lc = wc * 64 + ni * 16 + fr;
        uint2 pk;
        pk.x = (unsigned)f2b(acc[mi][ni][0]) | ((unsigned)f2b(acc[mi][ni][1]) << 16);
        pk.y = (unsigned)f2b(acc[mi][ni][2]) | ((unsigned)f2b(acc[mi][ni][3]) << 16);
        if (mode == 1) {
          int bb2 = grow >> 11, s = grow & (SS - 1);
          *(uint2*)(Vtl + ((long)bb2 * DD + vcol0 + lc) * SS + s) = pk;
        } else if (mode == 2) {
          int bb2 = grow / KPAD, j = grow - bb2 * KPAD;
          *(uint2*)(Vt + ((long)bb2 * DD + vcol0 + lc) * KPAD + j) = pk;
        } else if (mode == 3) {
          if (grow < 16) {
#pragma unroll
            for (int r = 0; r < 4; ++r) {
              int g2 = grow + r;
              K8[((long)(g2 >> 3) * 16 + (g2 & 7)) * DD + colBase + lc] =
                  f2b(acc[mi][ni][r]);
            }
          }
        } else {
          if (grow < 16) {
            *(uint2*)(Vt8 + ((long)(grow >> 3) * DD + vcol0 + lc) * 32 + (grow & 7)) = pk;
          }
        }
      }
    }
    if (mode == 4) {
#pragma unroll
      for (int e = 0; e < 6; ++e) {
        int id = tid + e * 256;
        int bb2 = id / 768, rem = id % 768;
        int c = rem / 6, ch = rem % 6;
        *(uint2*)(Vt8 + ((long)bb2 * DD + vcol0 + c) * 32 + 8 + ch * 4) = uint2{0u, 0u};
      }
    }
  }
}

// ---------------- final GEMM, split-K=3 into f32 partials -------------------
__global__ __launch_bounds__(256) void gemm_final_sk(const unsigned short* __restrict__ A,
                                                     const unsigned short* __restrict__ BT,
                                                     float* __restrict__ Cpart) {
  __shared__ unsigned short As[2][128 * 32];
  __shared__ unsigned short Bs[2][128 * 32];
  constexpr int N = 768, K = 2304, CK = 768;
  const int tid = threadIdx.x;
  const int lane = tid & 63;
  const int wv = tid >> 6;
  const int wr = wv >> 1, wc = wv & 1;
  const int z = blockIdx.z;

  int lin = blockIdx.y * gridDim.x + blockIdx.x;   // 192 blocks/plane
  int swz = (lin & 7) * 24 + (lin >> 3);
  const long rowBase = (long)(swz / 6) * 128;
  const long colBase = (long)(swz % 6) * 128;

  f32x4 acc[4][4];
#pragma unroll
  for (int i = 0; i < 4; ++i)
#pragma unroll
    for (int j = 0; j < 4; ++j)
#pragma unroll
      for (int r = 0; r < 4; ++r) acc[i][j][r] = 0.f;

  const int g0 = tid, g1 = tid + 256;
  const int r0 = g0 >> 2, k80 = (g0 & 3) ^ ((r0 >> 1) & 3);
  const int r1 = g1 >> 2, k81 = (g1 & 3) ^ ((r1 >> 1) & 3);
  const unsigned short* ga0 = A + (rowBase + r0) * (long)K + z * CK + k80 * 8;
  const unsigned short* ga1 = A + (rowBase + r1) * (long)K + z * CK + k81 * 8;
  const unsigned short* gb0 = BT + (colBase + r0) * (long)K + z * CK + k80 * 8;
  const unsigned short* gb1 = BT + (colBase + r1) * (long)K + z * CK + k81 * 8;

  const int k8 = lane >> 4;
  const int fr = lane & 15;
  int aoff[4], boff[4];
#pragma unroll
  for (int i = 0; i < 4; ++i) {
    int rowA = wr * 64 + i * 16 + fr;
    aoff[i] = (rowA * 4 + (k8 ^ ((rowA >> 1) & 3))) * 8;
    int rowB = wc * 64 + i * 16 + fr;
    boff[i] = (rowB * 4 + (k8 ^ ((rowB >> 1) & 3))) * 8;
  }

  auto stage = [&](int buf, int t) {
    int ko = t * 32;
    gload_lds16(ga0 + ko, &As[buf][g0 * 8]);
    gload_lds16(ga1 + ko, &As[buf][g1 * 8]);
    gload_lds16(gb0 + ko, &Bs[buf][g0 * 8]);
    gload_lds16(gb1 + ko, &Bs[buf][g1 * 8]);
  };

  constexpr int nk = CK >> 5;   // 24
  stage(0, 0);
  __syncthreads();
  for (int t = 0; t < nk; ++t) {
    int cur = t & 1;
    if (t + 1 < nk) stage(cur ^ 1, t + 1);
    bf16x8 af[4], bfr[4];
#pragma unroll
    for (int i = 0; i < 4; ++i) af[i] = *(const bf16x8*)(&As[cur][aoff[i]]);
#pragma unroll
    for (int i = 0; i < 4; ++i) bfr[i] = *(const bf16x8*)(&Bs[cur][boff[i]]);
#pragma unroll
    for (int mi = 0; mi < 4; ++mi)
#pragma unroll
      for (int ni = 0; ni < 4; ++ni)
        acc[mi][ni] = __builtin_amdgcn_mfma_f32_16x16x32_bf16(af[mi], bfr[ni], acc[mi][ni], 0, 0, 0);
    __syncthreads();
  }

  float* Cz = Cpart + (long)z * NTOK * DD;
  const int orow0 = (lane >> 4) * 4;
#pragma unroll
  for (int mi = 0; mi < 4; ++mi) {
    long gr = rowBase + wr * 64 + mi * 16 + orow0;
#pragma unroll
    for (int ni = 0; ni < 4; ++ni) {
      long gc = colBase + wc * 64 + ni * 16 + fr;
#pragma unroll
      for (int r = 0; r < 4; ++r)
        Cz[(gr + r) * (long)N + gc] = acc[mi][ni][r];
    }
  }
}

// ------- reduce partials, applying the folded-LN affine per branch ----------
__global__ __launch_bounds__(256) void reduce_out(const float* __restrict__ P,
                                                  const float* __restrict__ bias,
                                                  const float* __restrict__ sumb,
                                                  const float* __restrict__ sqb,
                                                  const float* __restrict__ Sbuf,
                                                  const float* __restrict__ Tbuf,
                                                  const float* __restrict__ fw,
                                                  float* __restrict__ out) {
  long i = (long)blockIdx.x * 256 + threadIdx.x;   // over NTOK*DD/4 f32x4
  int r = (int)(i / (DD / 4));
  int c4 = (int)(i % (DD / 4));
  int b = r >> 11;
  f32x4 o = *(const f32x4*)(bias + c4 * 4);
#pragma unroll
  for (int br = 0; br < 3; ++br) {
    float sum = sumb[br * NTOK + r];
    float sq  = sqb[br * NTOK + r];
    float mean = sum * (1.f / (float)DD);
    float var  = sq * (1.f / (float)DD) - mean * mean;
    float rs   = rsqrtf(var + 1e-5f);
    float gate = fw[b * 3 + br];
    f32x4 P4 = ((const f32x4*)(P + (long)br * NTOK * DD))[i];
    f32x4 S4 = *(const f32x4*)(Sbuf + br * DD + c4 * 4);
    f32x4 T4 = *(const f32x4*)(Tbuf + br * DD + c4 * 4);
#pragma unroll
    for (int e = 0; e < 4; ++e)
      o[e] += gate * (rs * (P4[e] - mean * S4[e]) + T4[e]);
  }
  ((f32x4*)out)[i] = o;
}

// ---------------- attention bodies (raw bf16 output + row stats) ------------
__device__ __forceinline__ void attn_flash_body(
    const unsigned short* __restrict__ QKV4,
    const unsigned short* __restrict__ KVg,
    const unsigned short* __restrict__ Vt,
    unsigned short* __restrict__ comb,
    float* __restrict__ sumb, float* __restrict__ sqb,
    unsigned short* smem) {
  unsigned short* Kl = smem;            // [2][64*64]
  unsigned short* Vl = smem + 8192;     // [2][64*64]
  unsigned short* Pl = smem + 16384;    // [4][16*68]
  int tid = threadIdx.x, w = tid >> 6, lane = tid & 63;
  int fr = lane & 15, g = lane >> 4;
  int b = blockIdx.y / HH, h = blockIdx.y % HH, hoff = h * 64;
  int qbase = blockIdx.x * 64 + w * 16;
  long qrow = (long)b * SS + qbase + fr;

  const unsigned short* qptr = QKV4 + qrow * 3072 + hoff + g * 8;
  bf16x8 bq0 = *(const bf16x8*)(qptr);
  bf16x8 bq1 = *(const bf16x8*)(qptr + 32);

  const int s0 = tid, s1 = tid + 256;
  const int r0 = s0 >> 3, c0 = (s0 & 7) ^ (r0 & 7);
  const int r1 = s1 >> 3, c1 = (s1 & 7) ^ (r1 & 7);
  const unsigned short* kg_b = KVg + (long)b * KPAD * 1536 + hoff;
  const unsigned short* vt_b = Vt + ((long)b * DD + hoff) * KPAD;

  auto stage = [&](int buf, int t0) {
    gload_lds16(kg_b + (long)(t0 * 64 + r0) * 1536 + c0 * 8, &Kl[buf * 4096 + s0 * 8]);
    gload_lds16(kg_b + (long)(t0 * 64 + r1) * 1536 + c1 * 8, &Kl[buf * 4096 + s1 * 8]);
    gload_lds16(vt_b + (long)r0 * KPAD + t0 * 64 + c0 * 8, &Vl[buf * 4096 + s0 * 8]);
    gload_lds16(vt_b + (long)r1 * KPAD + t0 * 64 + c1 * 8, &Vl[buf * 4096 + s1 * 8]);
  };

  f32x4 oacc[4];
#pragma unroll
  for (int mf = 0; mf < 4; ++mf)
#pragma unroll
    for (int r = 0; r < 4; ++r) oacc[mf][r] = 0.f;
  float m = -3.0e38f, l = 0.f;

  stage(0, 0);
  asm volatile("s_waitcnt vmcnt(0)" ::: "memory");
  __syncthreads();

  for (int t = 0; t < NKT; ++t) {
    int cur = t & 1;
    if (t + 1 < NKT) stage(cur ^ 1, t + 1);

    f32x4 st[4];
#pragma unroll
    for (int kt = 0; kt < 4; ++kt) {
      int row = kt * 16 + fr;
      bf16x8 a0 = *(const bf16x8*)(&Kl[cur * 4096 + (row * 8 + (g ^ (row & 7))) * 8]);
      bf16x8 a1 = *(const bf16x8*)(&Kl[cur * 4096 + (row * 8 + ((4 + g) ^ (row & 7))) * 8]);
      f32x4 z = {0.f, 0.f, 0.f, 0.f};
      z = __builtin_amdgcn_mfma_f32_16x16x32_bf16(a0, bq0, z, 0, 0, 0);
      st[kt] = __builtin_amdgcn_mfma_f32_16x16x32_bf16(a1, bq1, z, 0, 0, 0);
    }

    float tm = -3.0e38f;
#pragma unroll
    for (int kt = 0; kt < 4; ++kt)
#pragma unroll
      for (int r = 0; r < 4; ++r) {
        int key = t * 64 + kt * 16 + g * 4 + r;
        float s = (key < KSEL) ? st[kt][r] * 0.125f : -1.0e30f;
        st[kt][r] = s;
        tm = fmaxf(tm, s);
      }
    tm = fmaxf(tm, __shfl_xor(tm, 16, 64));
    tm = fmaxf(tm, __shfl_xor(tm, 32, 64));
    float newm = fmaxf(m, tm);
    float f = __expf(m - newm);
    float tsum = 0.f;
#pragma unroll
    for (int kt = 0; kt < 4; ++kt)
#pragma unroll
      for (int r = 0; r < 4; ++r) {
        float e = __expf(st[kt][r] - newm);
        st[kt][r] = e;
        tsum += e;
      }
    tsum += __shfl_xor(tsum, 16, 64);
    tsum += __shfl_xor(tsum, 32, 64);
    l = l * f + tsum;
    m = newm;
#pragma unroll
    for (int mf = 0; mf < 4; ++mf)
#pragma unroll
      for (int r = 0; r < 4; ++r) oacc[mf][r] *= f;

    unsigned short* pw = &Pl[w * 1088 + fr * 68 + g * 4];
#pragma unroll
    for (int kt = 0; kt < 4; ++kt) {
      uint2 pk;
      pk.x = (unsigned)f2b(st[kt][0]) | ((unsigned)f2b(st[kt][1]) << 16);
      pk.y = (unsigned)f2b(st[kt][2]) | ((unsigned)f2b(st[kt][3]) << 16);
      *(uint2*)(pw + kt * 16) = pk;
    }

    const unsigned short* prd = &Pl[w * 1088 + fr * 68];
#pragma unroll
    for (int ks2 = 0; ks2 < 2; ++ks2) {
      bf16x8 pf = *(const bf16x8*)(prd + ks2 * 32 + g * 8);
#pragma unroll
      for (int mf = 0; mf < 4; ++mf) {
        int vr = mf * 16 + fr;
        int vc = ks2 * 4 + g;
        bf16x8 vf = *(const bf16x8*)(&Vl[cur * 4096 + (vr * 8 + (vc ^ (vr & 7))) * 8]);
        oacc[mf] = __builtin_amdgcn_mfma_f32_16x16x32_bf16(vf, pf, oacc[mf], 0, 0, 0);
      }
    }

    asm volatile("s_waitcnt vmcnt(0)" ::: "memory");
    __syncthreads();
  }

  float inv = 1.f / l;
  unsigned short* orow = comb + qrow * 2304 + hoff;
  float rsum = 0.f, rsq = 0.f;
#pragma unroll
  for (int mf = 0; mf < 4; ++mf) {
    float v0 = oacc[mf][0] * inv, v1 = oacc[mf][1] * inv;
    float v2 = oacc[mf][2] * inv, v3 = oacc[mf][3] * inv;
    rsum += v0 + v1 + v2 + v3;
    rsq  += v0 * v0 + v1 * v1 + v2 * v2 + v3 * v3;
    uint2 pk;
    pk.x = (unsigned)f2b(v0) | ((unsigned)f2b(v1) << 16);
    pk.y = (unsigned)f2b(v2) | ((unsigned)f2b(v3) << 16);
    *(uint2*)(orow + mf * 16 + g * 4) = pk;
  }
  rsum += __shfl_xor(rsum, 16, 64);
  rsum += __shfl_xor(rsum, 32, 64);
  rsq  += __shfl_xor(rsq, 16, 64);
  rsq  += __shfl_xor(rsq, 32, 64);
  if (lane < 16) {
    atomicAdd(&sumb[qrow], rsum);
    atomicAdd(&sqb[qrow], rsq);
  }
}

__device__ __forceinline__ void attn_win_body(
    const unsigned short* __restrict__ QKV,
    const unsigned short* __restrict__ K8,
    const unsigned short* __restrict__ Vt,
    unsigned short* __restrict__ comb, int brOff,
    float* __restrict__ sumb, float* __restrict__ sqb,
    int LD, int QO, long VSTR, bool local,
    unsigned short* smem) {
  int tid = threadIdx.x, w = tid >> 6, lane = tid & 63;
  int fr = lane & 15, g = lane >> 4;
  int b = blockIdx.y / HH, h = blockIdx.y % HH, hoff = h * 64;
  int qbase = blockIdx.x * 64 + w * 16;
  long qrow = (long)b * SS + qbase + fr;

  const unsigned short* qptr = QKV + qrow * LD + QO + hoff + g * 8;
  bf16x8 bq0 = *(const bf16x8*)(qptr);
  bf16x8 bq1 = *(const bf16x8*)(qptr + 32);

  int kstart = qbase - 8;
  if (kstart < 0) kstart = 0;
  if (kstart > SS - 32) kstart = SS - 32;

  f32x4 st[2];
  if (local) {
#pragma unroll
    for (int kt = 0; kt < 2; ++kt) {
      const unsigned short* kp =
          QKV + ((long)b * SS + kstart + kt * 16 + fr) * LD + 1536 + hoff + g * 8;
      bf16x8 a0 = *(const bf16x8*)(kp);
      bf16x8 a1 = *(const bf16x8*)(kp + 32);
      f32x4 z = {0.f, 0.f, 0.f, 0.f};
      z = __builtin_amdgcn_mfma_f32_16x16x32_bf16(a0, bq0, z, 0, 0, 0);
      st[kt] = __builtin_amdgcn_mfma_f32_16x16x32_bf16(a1, bq1, z, 0, 0, 0);
    }
  } else {
    const unsigned short* kp = K8 + ((long)b * 16 + fr) * DD + hoff + g * 8;
    bf16x8 a0 = *(const bf16x8*)(kp);
    bf16x8 a1 = *(const bf16x8*)(kp + 32);
    f32x4 z = {0.f, 0.f, 0.f, 0.f};
    z = __builtin_amdgcn_mfma_f32_16x16x32_bf16(a0, bq0, z, 0, 0, 0);
    st[0] = __builtin_amdgcn_mfma_f32_16x16x32_bf16(a1, bq1, z, 0, 0, 0);
    st[1] = f32x4{0.f, 0.f, 0.f, 0.f};
  }

  float m = -3.0e38f;
#pragma unroll
  for (int kt = 0; kt < 2; ++kt)
#pragma unroll
    for (int r = 0; r < 4; ++r) {
      int idx = kt * 16 + g * 4 + r;
      bool valid;
      if (local) {
        int rel = kstart + idx - qbase - fr;
        valid = (rel >= -8) && (rel <= 8);
      } else {
        valid = (idx < 8);
      }
      float s = valid ? st[kt][r] * 0.125f : -1.0e30f;
      st[kt][r] = s;
      m = fmaxf(m, s);
    }
  m = fmaxf(m, __shfl_xor(m, 16, 64));
  m = fmaxf(m, __shfl_xor(m, 32, 64));

  float lsum = 0.f;
#pragma unroll
  for (int kt = 0; kt < 2; ++kt)
#pragma unroll
    for (int r = 0; r < 4; ++r) {
      float e = __expf(st[kt][r] - m);
      st[kt][r] = e;
      lsum += e;
    }
  lsum += __shfl_xor(lsum, 16, 64);
  lsum += __shfl_xor(lsum, 32, 64);

  unsigned short* pl = smem + w * 640 + fr * 40 + g * 4;
#pragma unroll
  for (int kt = 0; kt < 2; ++kt) {
    uint2 pk;
    pk.x = (unsigned)f2b(st[kt][0]) | ((unsigned)f2b(st[kt][1]) << 16);
    pk.y = (unsigned)f2b(st[kt][2]) | ((unsigned)f2b(st[kt][3]) << 16);
    *(uint2*)(pl + kt * 16) = pk;
  }

  f32x4 oacc[4];
#pragma unroll
  for (int mf = 0; mf < 4; ++mf)
#pragma unroll
    for (int r = 0; r < 4; ++r) oacc[mf][r] = 0.f;

  const unsigned short* pr = smem + w * 640 + fr * 40 + g * 8;
  bf16x8 pf = *(const bf16x8*)(pr);
  long kb2 = local ? kstart : 0;
#pragma unroll
  for (int mf = 0; mf < 4; ++mf) {
    const unsigned short* vp =
        Vt + ((long)b * DD + hoff + mf * 16 + fr) * VSTR + kb2 + g * 8;
    bf16x8 vf = *(const bf16x8*)(vp);
    oacc[mf] = __builtin_amdgcn_mfma_f32_16x16x32_bf16(vf, pf, oacc[mf], 0, 0, 0);
  }

  float inv = 1.f / lsum;
  unsigned short* orow = comb + qrow * 2304 + brOff + hoff;
  float rsum = 0.f, rsq = 0.f;
#pragma unroll
  for (int mf = 0; mf < 4; ++mf) {
    float v0 = oacc[mf][0] * inv, v1 = oacc[mf][1] * inv;
    float v2 = oacc[mf][2] * inv, v3 = oacc[mf][3] * inv;
    rsum += v0 + v1 + v2 + v3;
    rsq  += v0 * v0 + v1 * v1 + v2 * v2 + v3 * v3;
    uint2 pk;
    pk.x = (unsigned)f2b(v0) | ((unsigned)f2b(v1) << 16);
    pk.y = (unsigned)f2b(v2) | ((unsigned)f2b(v3) << 16);
    *(uint2*)(orow + mf * 16 + g * 4) = pk;
  }
  rsum += __shfl_xor(rsum, 16, 64);
  rsum += __shfl_xor(rsum, 32, 64);
  rsq  += __shfl_xor(rsq, 16, 64);
  rsq  += __shfl_xor(rsq, 32, 64);
  if (lane < 16) {
    atomicAdd(&sumb[qrow], rsum);
    atomicAdd(&sqb[qrow], rsq);
  }
}

// ---------------- merged attention dispatch (z: 0=global 1=local 2=temporal)
__global__ __launch_bounds__(256) void attn_all(
    const unsigned short* __restrict__ QKV4,
    const unsigned short* __restrict__ KVg,
    const unsigned short* __restrict__ Vt,
    const unsigned short* __restrict__ Qt,
    const unsigned short* __restrict__ K8,
    const unsigned short* __restrict__ Vt8,
    const unsigned short* __restrict__ Vtl,
    unsigned short* __restrict__ comb,
    float* __restrict__ sumb, float* __restrict__ sqb) {
  __shared__ unsigned short smem[20736];
  int z = blockIdx.z;
  if (z == 0) {
    attn_flash_body(QKV4, KVg, Vt, comb, sumb, sqb, smem);
  } else if (z == 1) {
    attn_win_body(QKV4, nullptr, Vtl, comb, 768, sumb + NTOK, sqb + NTOK,
                  3072, 768, SS, true, smem);
  } else {
    attn_win_body(Qt, K8, Vt8, comb, 1536, sumb + 2 * NTOK, sqb + 2 * NTOK,
                  768, 0, 32, false, smem);
  }
}

// ---------------- launcher ---------------------------------------------------
extern "C" void kernel_launch(void* const* d_in, const int* in_sizes, int n_in,
                              void* d_out, int out_size, void* d_ws, size_t ws_size,
                              hipStream_t stream) {
  const float* x        = (const float*)d_in[0];
  const float* wgq      = (const float*)d_in[1];
  const float* wgk      = (const float*)d_in[2];
  const float* wgv      = (const float*)d_in[3];
  const float* wlq      = (const float*)d_in[4];
  const float* wlk      = (const float*)d_in[5];
  const float* wlv      = (const float*)d_in[6];
  const float* wtq      = (const float*)d_in[7];
  const float* wtk      = (const float*)d_in[8];
  const float* wtv      = (const float*)d_in[9];
  const float* w_out    = (const float*)d_in[10];
  const float* b_out    = (const float*)d_in[11];
  const float* w_gate   = (const float*)d_in[12];
  const float* b_gate   = (const float*)d_in[13];
  const float* w_sparse = (const float*)d_in[14];
  const float* b_sparse = (const float*)d_in[15];
  const float* g_gamma  = (const float*)d_in[16];
  const float* g_beta   = (const float*)d_in[17];
  const float* l_gamma  = (const float*)d_in[18];
  const float* l_beta   = (const float*)d_in[19];
  const float* t_gamma  = (const float*)d_in[20];
  const float* t_beta   = (const float*)d_in[21];
  float* outp = (float*)d_out;

  unsigned short* xb    = (unsigned short*)d_ws;
  unsigned short* xpb   = xb    + (long)NTOK * DD;
  unsigned short* WTx4  = xpb   + (long)NTOK * DD;        // [3072][768]
  unsigned short* WTkv  = WTx4  + (long)3072 * DD;        // [1536][768]
  unsigned short* WTqt  = WTkv  + (long)1536 * DD;        // [768][768]
  unsigned short* WTtkv = WTqt  + (long)DD * DD;          // [1536][768]
  unsigned short* WTo   = WTtkv + (long)1536 * DD;        // [768][2304] (gamma-folded)
  unsigned short* QKV4  = WTo   + (long)DD * 2304;        // [4096][3072]
  unsigned short* Qt    = QKV4  + (long)NTOK * 3072;      // [4096][768]
  unsigned short* KVg   = Qt    + (long)NTOK * DD;        // [896][1536]
  unsigned short* K8    = KVg   + (long)BB * KPAD * 1536; // [2][16][768]
  unsigned short* Vt8   = K8    + (long)BB * 16 * DD;     // [2][768][32]
  unsigned short* Vt    = Vt8   + (long)BB * DD * 32;     // [2][768][448]
  unsigned short* Vtl   = Vt    + (long)BB * DD * KPAD;   // [2][768][2048]
  unsigned short* comb  = Vtl   + (long)BB * DD * SS;     // [4096][2304] raw attn
  float* Cpart   = (float*)(comb + (long)NTOK * 2304);    // [3][4096][768]
  float* imp     = Cpart + 3L * NTOK * DD;
  float* partial = imp + NTOK;
  float* fw      = partial + 32 * DD;
  int*   sel     = (int*)(fw + 8);
  float* sumb    = (float*)(sel + 1024);                  // [3][4096]
  float* sqb     = sumb + 3 * NTOK;                       // [3][4096]
  float* Sbuf    = sqb + 3 * NTOK;                        // [3][768]
  float* Tbuf    = Sbuf + 3 * DD;                         // [3][768]

  hipMemsetAsync(sumb, 0, (size_t)(6 * NTOK + 6 * DD) * sizeof(float), stream);

  mega_pre<<<SS + 6912 + 32, 256, 0, stream>>>(
      x, w_sparse, b_sparse, xb, xpb, imp,
      wgq, wgk, wgv, wlq, wlk, wlv, wtq, wtk, wtv, w_out,
      g_gamma, l_gamma, t_gamma, g_beta, l_beta, t_beta,
      WTx4, WTkv, WTqt, WTtkv, WTo, Sbuf, Tbuf, partial);
  topk_gate2<<<4, 1024, 0, stream>>>(imp, sel, partial, w_gate, b_gate, fw);

  gemm_multi<<<1056, 256, 0, stream>>>(xb, WTx4, QKV4, WTkv, KVg,
                                       xpb, WTqt, Qt, WTtkv, sel,
                                       K8, Vt8, Vt, Vtl);

  attn_all<<<dim3(32, BB * HH, 3), 256, 0, stream>>>(QKV4, KVg, Vt, Qt, K8, Vt8,
                                                     Vtl, comb, sumb, sqb);

  gemm_final_sk<<<dim3(6, 32, 3), 256, 0, stream>>>(comb, WTo, Cpart);
  reduce_out<<<NTOK * DD / 4 / 256, 256, 0, stream>>>(Cpart, b_out, sumb, sqb,
                                                      Sbuf, Tbuf, fw, outp);
}

// Round 21
// 166.982 us; speedup vs baseline: 1.0856x; 1.0328x over previous
//
#include <hip/hip_runtime.h>
#include <cstdint>

// Problem constants
constexpr int BB   = 2;
constexpr int SS   = 2048;
constexpr int DD   = 768;
constexpr int HH   = 12;
constexpr int NTOK = BB * SS;          // 4096
constexpr int KSEL = 409;              // int((1-0.8)*2048)
constexpr int KPAD = 448;              // 7 kv-tiles of 64
constexpr int NKT  = 7;                // kv tiles of 64 keys

typedef __bf16 bf16x8 __attribute__((ext_vector_type(8)));
typedef float  f32x4  __attribute__((ext_vector_type(4)));

__device__ __forceinline__ float b2f(unsigned short u) {
  return __uint_as_float(((unsigned)u) << 16);
}
__device__ __forceinline__ unsigned short f2b(float f) {
  unsigned u = __float_as_uint(f);
  u += 0x7fffu + ((u >> 16) & 1u);   // RNE
  return (unsigned short)(u >> 16);
}
__device__ __forceinline__ unsigned long long shfl_xor_u64(unsigned long long v, int m) {
  unsigned lo = (unsigned)v, hi = (unsigned)(v >> 32);
  lo = __shfl_xor(lo, m, 64);
  hi = __shfl_xor(hi, m, 64);
  return ((unsigned long long)hi << 32) | lo;
}

__device__ __forceinline__ void gload_lds16(const void* gsrc, void* ldst) {
  __builtin_amdgcn_global_load_lds(
      (__attribute__((address_space(1))) void*)(gsrc),
      (__attribute__((address_space(3))) void*)(ldst), 16, 0, 0);
}

// ------- mega_pre: prep_imp (2048) | weight transpose (6912) | gate1 (32) ---
__global__ __launch_bounds__(256) void mega_pre(
    const float* __restrict__ x, const float* __restrict__ wsp,
    const float* __restrict__ bsp,
    unsigned short* __restrict__ xb, unsigned short* __restrict__ xpb,
    float* __restrict__ imp,
    const float* w0, const float* w1, const float* w2, const float* w3,
    const float* w4, const float* w5, const float* w6, const float* w7,
    const float* w8, const float* w9,
    const float* __restrict__ gg, const float* __restrict__ lgam,
    const float* __restrict__ tg,
    const float* __restrict__ gb, const float* __restrict__ lbet,
    const float* __restrict__ tb,
    unsigned short* __restrict__ WTx4, unsigned short* __restrict__ WTkv,
    unsigned short* __restrict__ WTqt, unsigned short* __restrict__ WTtkv,
    unsigned short* __restrict__ WTo,
    float* __restrict__ Sbuf, float* __restrict__ Tbuf,
    float* __restrict__ partial) {
  __shared__ float tile[32][33];
  __shared__ float gsh[32], bsh[32];
  __shared__ float redS[8][32], redT[8][32];
  int id = blockIdx.x;
  int tid = threadIdx.x;

  if (id < SS) {
    int srow = id;
    const float* xr0 = x + (long)srow * DD;
    const float* xr1 = x + (long)(SS + srow) * DD;
    float acc0 = 0.f, acc1 = 0.f;
#pragma unroll
    for (int k = 0; k < 3; ++k) {
      int c = tid + k * 256;
      int j2 = c & ~1;
      float freq = __expf((float)j2 * -0.011992630692677323f);
      float ang = (float)srow * freq;
      float pe = (c & 1) ? __cosf(ang) : __sinf(ang);
      float w = wsp[c];
      float x0 = xr0[c], x1 = xr1[c];
      xb[(long)srow * DD + c]        = f2b(x0);
      xb[(long)(SS + srow) * DD + c] = f2b(x1);
      xpb[(long)srow * DD + c]        = f2b(x0 + pe);
      xpb[(long)(SS + srow) * DD + c] = f2b(x1 + pe);
      acc0 += x0 * w;
      acc1 += x1 * w;
    }
#pragma unroll
    for (int m = 1; m < 64; m <<= 1) {
      acc0 += __shfl_xor(acc0, m, 64);
      acc1 += __shfl_xor(acc1, m, 64);
    }
    __shared__ float red[8];
    int wv = tid >> 6, lane = tid & 63;
    if (lane == 0) { red[wv] = acc0; red[4 + wv] = acc1; }
    __syncthreads();
    if (tid == 0) {
      imp[srow]      = red[0] + red[1] + red[2] + red[3] + bsp[0];
      imp[SS + srow] = red[4] + red[5] + red[6] + red[7] + bsp[0];
    }
  } else if (id < SS + 6912) {
    int tidx = id - SS;
    int z, bx, by;
    if (tidx < 5184) { z = tidx / 576; int rem = tidx % 576; by = rem / 24; bx = rem % 24; }
    else             { z = 9; int rem = tidx - 5184; by = rem / 24; bx = rem % 24; }
    const float* srcs[10] = {w0, w1, w2, w3, w4, w5, w6, w7, w8, w9};
    const float* src = srcs[z];
    unsigned short* dst;
    int R = DD;
    switch (z) {
      case 0: dst = WTx4;                       break;
      case 1: dst = WTkv;                       break;
      case 2: dst = WTkv + (long)DD * DD;       break;
      case 3: dst = WTx4 + (long)DD * DD;       break;
      case 4: dst = WTx4 + (long)2 * DD * DD;   break;
      case 5: dst = WTx4 + (long)3 * DD * DD;   break;
      case 6: dst = WTqt;                       break;
      case 7: dst = WTtkv;                      break;
      case 8: dst = WTtkv + (long)DD * DD;      break;
      default: dst = WTo; R = 2304;             break;
    }
    int r0 = by * 32, c0 = bx * 32;
    int tx = tid & 31, ty = tid >> 5;
    for (int i = ty; i < 32; i += 8) tile[i][tx] = src[(long)(r0 + i) * DD + c0 + tx];
    if (z == 9 && ty == 0) {
      int kk = r0 + tx;                    // tile is single-branch (768 % 32 == 0)
      gsh[tx] = (kk < 768) ? gg[kk] : (kk < 1536) ? lgam[kk - 768] : tg[kk - 1536];
      bsh[tx] = (kk < 768) ? gb[kk] : (kk < 1536) ? lbet[kk - 768] : tb[kk - 1536];
    }
    __syncthreads();
    if (z == 9) {
      float gamv = gsh[tx];
      for (int i = ty; i < 32; i += 8)
        dst[(long)(c0 + i) * R + r0 + tx] = f2b(tile[tx][i] * gamv);
      float pS = 0.f, pT = 0.f;
      for (int i = ty; i < 32; i += 8) {
        float wv = tile[i][tx];
        pS += gsh[i] * wv;
        pT += bsh[i] * wv;
      }
      redS[ty][tx] = pS; redT[ty][tx] = pT;
      __syncthreads();
      if (ty == 0) {
        float s = 0.f, t2 = 0.f;
#pragma unroll
        for (int j = 0; j < 8; ++j) { s += redS[j][tx]; t2 += redT[j][tx]; }
        int br = r0 / 768;
        atomicAdd(&Sbuf[br * DD + c0 + tx], s);
        atomicAdd(&Tbuf[br * DD + c0 + tx], t2);
      }
    } else {
      for (int i = ty; i < 32; i += 8)
        dst[(long)(c0 + i) * R + r0 + tx] = f2b(tile[tx][i]);
    }
  } else {
    int rem = id - SS - 6912;            // 0..31
    int chunk = rem & 15, b = rem >> 4;
    for (int c = tid; c < DD; c += 256) {
      const float* xp = x + ((long)(b * SS + chunk * 128)) * DD + c;
      float acc = 0.f;
      for (int s2 = 0; s2 < 128; ++s2) acc += xp[(long)s2 * DD];
      partial[(long)(b * 16 + chunk) * DD + c] = acc;
    }
  }
}

// ------- topk (blocks 0..1, hybrid bitonic) + gate2 (blocks 2..3) -----------
__global__ __launch_bounds__(1024) void topk_gate2(
    const float* __restrict__ imp, int* __restrict__ sel,
    const float* __restrict__ partial, const float* __restrict__ w_gate,
    const float* __restrict__ b_gate, float* __restrict__ fw) {
  int tid = threadIdx.x;
  if (blockIdx.x < 2) {
    __shared__ unsigned long long keys[SS];
    int b = blockIdx.x;
    for (int i = tid; i < SS; i += 1024) {
      float v = imp[b * SS + i];
      unsigned u = __float_as_uint(v);
      u = (u & 0x80000000u) ? ~u : (u | 0x80000000u);
      unsigned du = ~u;
      keys[i] = ((unsigned long long)du << 32) | (unsigned)i;
    }
    __syncthreads();
    for (int k = 2; k <= SS; k <<= 1) {
      for (int j = k >> 1; j >= 64; j >>= 1) {
        for (int i = tid; i < SS; i += 1024) {
          int p = i ^ j;
          if (p > i) {
            unsigned long long a = keys[i], bb = keys[p];
            bool up = ((i & k) == 0);
            if ((a > bb) == up) { keys[i] = bb; keys[p] = a; }
          }
        }
        __syncthreads();
      }
      unsigned long long k0 = keys[tid], k1 = keys[tid + 1024];
      bool up0 = ((tid & k) == 0);
      bool up1 = (((tid + 1024) & k) == 0);
      int j0 = (k >> 1) < 32 ? (k >> 1) : 32;
      for (int j = j0; j >= 1; j >>= 1) {
        bool low = ((tid & j) == 0);
        unsigned long long p0 = shfl_xor_u64(k0, j);
        k0 = ((low == up0) == (k0 < p0)) ? k0 : p0;
        unsigned long long p1 = shfl_xor_u64(k1, j);
        k1 = ((low == up1) == (k1 < p1)) ? k1 : p1;
      }
      keys[tid] = k0; keys[tid + 1024] = k1;
      __syncthreads();
    }
    for (int i = tid; i < KSEL; i += 1024) sel[b * KSEL + i] = (int)(keys[i] & 0xffffffffu);
  } else {
    __shared__ float meanbuf[DD];
    __shared__ float lg[3];
    int b = blockIdx.x - 2;
    if (tid < DD) {
      float acc = 0.f;
      for (int p = 0; p < 16; ++p) acc += partial[(long)(b * 16 + p) * DD + tid];
      meanbuf[tid] = acc * (1.0f / (float)SS);
    }
    __syncthreads();
    if (tid < 3) {
      float acc = b_gate[tid];
      for (int d = 0; d < DD; ++d) acc += meanbuf[d] * w_gate[d * 3 + tid];
      lg[tid] = acc;
    }
    __syncthreads();
    if (tid == 0) {
      float mx = fmaxf(lg[0], fmaxf(lg[1], lg[2]));
      float e0 = expf(lg[0] - mx), e1 = expf(lg[1] - mx), e2 = expf(lg[2] - mx);
      float inv = 1.f / (e0 + e1 + e2);
      fw[b * 3 + 0] = e0 * inv; fw[b * 3 + 1] = e1 * inv; fw[b * 3 + 2] = e2 * inv;
    }
  }
}

// ---------------- fused projection GEMMs (all K=768, 128x128 tiles) ---------
__global__ __launch_bounds__(256) void gemm_multi(
    const unsigned short* __restrict__ xb,    const unsigned short* __restrict__ WTx4,
    unsigned short* __restrict__ QKV4,
    const unsigned short* __restrict__ WTkv,  unsigned short* __restrict__ KVg,
    const unsigned short* __restrict__ xpb,   const unsigned short* __restrict__ WTqt,
    unsigned short* __restrict__ Qt,
    const unsigned short* __restrict__ WTtkv,
    const int* __restrict__ sel,
    unsigned short* __restrict__ K8, unsigned short* __restrict__ Vt8,
    unsigned short* __restrict__ Vt, unsigned short* __restrict__ Vtl) {
  __shared__ unsigned short AsB[2][4096];
  __shared__ unsigned short BsB[2][4096];
  constexpr int K = DD;
  const int tid = threadIdx.x;
  const int lane = tid & 63;
  const int wv = tid >> 6;
  const int wr = wv >> 1, wc = wv & 1;

  int lin = blockIdx.x;
  int xcd = lin & 7, idx = lin >> 3;     // idx in [0,132)
  const unsigned short* BT;
  int ntx, tile, region;
  if (idx < 96) {
    region = 0; BT = WTx4; ntx = 24;
    int r = (xcd >> 2) * 16 + (idx & 15);
    int c = (xcd & 3) * 6 + (idx >> 4);
    tile = r * 24 + c;
  } else {
    int e = xcd * 36 + (idx - 96);       // 0..287
    if (e < 84)       { region = 1; BT = WTkv;  ntx = 12; tile = e; }
    else if (e < 276) { region = 2; BT = WTqt;  ntx = 6;  tile = e - 84; }
    else              { region = 3; BT = WTtkv; ntx = 12; tile = e - 276; }
  }
  const long rowBase = (long)(tile / ntx) * 128;
  const long colBase = (long)(tile % ntx) * 128;

  auto arow = [&](int r) -> const unsigned short* {
    long grow = rowBase + r;
    if (region == 0) return xb + grow * (long)K;
    if (region == 2) return xpb + grow * (long)K;
    if (region == 1) {
      int bb2 = (int)(grow / KPAD), j = (int)(grow % KPAD);
      int srow = (j < KSEL) ? sel[bb2 * KSEL + j] : 0;
      return xb + ((long)bb2 * SS + srow) * (long)K;
    }
    if (grow < 16) {
      int bb2 = (int)grow >> 3, j = ((int)grow & 7) * 256;
      return xpb + ((long)bb2 * SS + j) * (long)K;
    }
    return xpb;
  };

  f32x4 acc[4][4];
#pragma unroll
  for (int i = 0; i < 4; ++i)
#pragma unroll
    for (int j = 0; j < 4; ++j)
#pragma unroll
      for (int r = 0; r < 4; ++r) acc[i][j][r] = 0.f;

  const int g0 = tid, g1 = tid + 256;
  const int r0 = g0 >> 2, k80 = (g0 & 3) ^ ((r0 >> 1) & 3);
  const int r1 = g1 >> 2, k81 = (g1 & 3) ^ ((r1 >> 1) & 3);
  const unsigned short* ga0 = arow(r0) + k80 * 8;
  const unsigned short* ga1 = arow(r1) + k81 * 8;
  const unsigned short* gb0 = BT + (colBase + r0) * (long)K + k80 * 8;
  const unsigned short* gb1 = BT + (colBase + r1) * (long)K + k81 * 8;

  const int k8 = lane >> 4;
  const int fr = lane & 15;
  int aoff[4], boff[4];
#pragma unroll
  for (int i = 0; i < 4; ++i) {
    int rowA = wr * 64 + i * 16 + fr;
    aoff[i] = (rowA * 4 + (k8 ^ ((rowA >> 1) & 3))) * 8;
    int rowB = wc * 64 + i * 16 + fr;
    boff[i] = (rowB * 4 + (k8 ^ ((rowB >> 1) & 3))) * 8;
  }

  auto stage = [&](int buf, int t) {
    int ko = t * 32;
    gload_lds16(ga0 + ko, &AsB[buf][g0 * 8]);
    gload_lds16(ga1 + ko, &AsB[buf][g1 * 8]);
    gload_lds16(gb0 + ko, &BsB[buf][g0 * 8]);
    gload_lds16(gb1 + ko, &BsB[buf][g1 * 8]);
  };

  constexpr int nk = K >> 5;   // 24
  stage(0, 0);
  __syncthreads();
  for (int t = 0; t < nk; ++t) {
    int cur = t & 1;
    if (t + 1 < nk) stage(cur ^ 1, t + 1);
    bf16x8 af[4], bfr[4];
#pragma unroll
    for (int i = 0; i < 4; ++i) af[i] = *(const bf16x8*)(&AsB[cur][aoff[i]]);
#pragma unroll
    for (int i = 0; i < 4; ++i) bfr[i] = *(const bf16x8*)(&BsB[cur][boff[i]]);
#pragma unroll
    for (int mi = 0; mi < 4; ++mi)
#pragma unroll
      for (int ni = 0; ni < 4; ++ni)
        acc[mi][ni] = __builtin_amdgcn_mfma_f32_16x16x32_bf16(af[mi], bfr[ni], acc[mi][ni], 0, 0, 0);
    __syncthreads();
  }

  // epilogue
  int mode, vcol0 = 0, N = 0;
  unsigned short* C = nullptr;
  if (region == 0)      { mode = (colBase >= 2304) ? 1 : 0; C = QKV4; N = 3072;
                          vcol0 = (int)colBase - 2304; }
  else if (region == 1) { mode = (colBase >= 768) ? 2 : 0;  C = KVg;  N = 1536;
                          vcol0 = (int)colBase - 768; }
  else if (region == 2) { mode = 0; C = Qt; N = 768; }
  else                  { mode = (colBase >= 768) ? 4 : 3;
                          vcol0 = (int)colBase - 768; }

  const int orow0 = (lane >> 4) * 4;
  if (mode == 0) {
#pragma unroll
    for (int mi = 0; mi < 4; ++mi) {
      long gr = rowBase + wr * 64 + mi * 16 + orow0;
#pragma unroll
      for (int ni = 0; ni < 4; ++ni) {
        long gc = colBase + wc * 64 + ni * 16 + fr;
#pragma unroll
        for (int r = 0; r < 4; ++r)
          C[(gr + r) * (long)N + gc] = f2b(acc[mi][ni][r]);
      }
    }
  } else {
#pragma unroll
    for (int mi = 0; mi < 4; ++mi) {
      int lr = wr * 64 + mi * 16 + orow0;
      int grow = (int)rowBase + lr;
#pragma unroll
      for (int ni = 0; ni < 4; ++ni) {
        int lc = wc * 64 + ni * 16 + fr;
        uint2 pk;
        pk.x = (unsigned)f2b(acc[mi][ni][0]) | ((unsigned)f2b(acc[mi][ni][1]) << 16);
        pk.y = (unsigned)f2b(acc[mi][ni][2]) | ((unsigned)f2b(acc[mi][ni][3]) << 16);
        if (mode == 1) {
          int bb2 = grow >> 11, s = grow & (SS - 1);
          *(uint2*)(Vtl + ((long)bb2 * DD + vcol0 + lc) * SS + s) = pk;
        } else if (mode == 2) {
          int bb2 = grow / KPAD, j = grow - bb2 * KPAD;
          *(uint2*)(Vt + ((long)bb2 * DD + vcol0 + lc) * KPAD + j) = pk;
        } else if (mode == 3) {
          if (grow < 16) {
#pragma unroll
            for (int r = 0; r < 4; ++r) {
              int g2 = grow + r;
              K8[((long)(g2 >> 3) * 16 + (g2 & 7)) * DD + colBase + lc] =
                  f2b(acc[mi][ni][r]);
            }
          }
        } else {
          if (grow < 16) {
            *(uint2*)(Vt8 + ((long)(grow >> 3) * DD + vcol0 + lc) * 32 + (grow & 7)) = pk;
          }
        }
      }
    }
    if (mode == 4) {
#pragma unroll
      for (int e = 0; e < 6; ++e) {
        int id = tid + e * 256;
        int bb2 = id / 768, rem = id % 768;
        int c = rem / 6, ch = rem % 6;
        *(uint2*)(Vt8 + ((long)bb2 * DD + vcol0 + c) * 32 + 8 + ch * 4) = uint2{0u, 0u};
      }
    }
  }
}

// ---------------- final GEMM, split-K=3 into f32 partials -------------------
__global__ __launch_bounds__(256) void gemm_final_sk(const unsigned short* __restrict__ A,
                                                     const unsigned short* __restrict__ BT,
                                                     float* __restrict__ Cpart) {
  __shared__ unsigned short As[2][128 * 32];
  __shared__ unsigned short Bs[2][128 * 32];
  constexpr int N = 768, K = 2304, CK = 768;
  const int tid = threadIdx.x;
  const int lane = tid & 63;
  const int wv = tid >> 6;
  const int wr = wv >> 1, wc = wv & 1;
  const int z = blockIdx.z;

  int lin = blockIdx.y * gridDim.x + blockIdx.x;   // 192 blocks/plane
  int swz = (lin & 7) * 24 + (lin >> 3);
  const long rowBase = (long)(swz / 6) * 128;
  const long colBase = (long)(swz % 6) * 128;

  f32x4 acc[4][4];
#pragma unroll
  for (int i = 0; i < 4; ++i)
#pragma unroll
    for (int j = 0; j < 4; ++j)
#pragma unroll
      for (int r = 0; r < 4; ++r) acc[i][j][r] = 0.f;

  const int g0 = tid, g1 = tid + 256;
  const int r0 = g0 >> 2, k80 = (g0 & 3) ^ ((r0 >> 1) & 3);
  const int r1 = g1 >> 2, k81 = (g1 & 3) ^ ((r1 >> 1) & 3);
  const unsigned short* ga0 = A + (rowBase + r0) * (long)K + z * CK + k80 * 8;
  const unsigned short* ga1 = A + (rowBase + r1) * (long)K + z * CK + k81 * 8;
  const unsigned short* gb0 = BT + (colBase + r0) * (long)K + z * CK + k80 * 8;
  const unsigned short* gb1 = BT + (colBase + r1) * (long)K + z * CK + k81 * 8;

  const int k8 = lane >> 4;
  const int fr = lane & 15;
  int aoff[4], boff[4];
#pragma unroll
  for (int i = 0; i < 4; ++i) {
    int rowA = wr * 64 + i * 16 + fr;
    aoff[i] = (rowA * 4 + (k8 ^ ((rowA >> 1) & 3))) * 8;
    int rowB = wc * 64 + i * 16 + fr;
    boff[i] = (rowB * 4 + (k8 ^ ((rowB >> 1) & 3))) * 8;
  }

  auto stage = [&](int buf, int t) {
    int ko = t * 32;
    gload_lds16(ga0 + ko, &As[buf][g0 * 8]);
    gload_lds16(ga1 + ko, &As[buf][g1 * 8]);
    gload_lds16(gb0 + ko, &Bs[buf][g0 * 8]);
    gload_lds16(gb1 + ko, &Bs[buf][g1 * 8]);
  };

  constexpr int nk = CK >> 5;   // 24
  stage(0, 0);
  __syncthreads();
  for (int t = 0; t < nk; ++t) {
    int cur = t & 1;
    if (t + 1 < nk) stage(cur ^ 1, t + 1);
    bf16x8 af[4], bfr[4];
#pragma unroll
    for (int i = 0; i < 4; ++i) af[i] = *(const bf16x8*)(&As[cur][aoff[i]]);
#pragma unroll
    for (int i = 0; i < 4; ++i) bfr[i] = *(const bf16x8*)(&Bs[cur][boff[i]]);
#pragma unroll
    for (int mi = 0; mi < 4; ++mi)
#pragma unroll
      for (int ni = 0; ni < 4; ++ni)
        acc[mi][ni] = __builtin_amdgcn_mfma_f32_16x16x32_bf16(af[mi], bfr[ni], acc[mi][ni], 0, 0, 0);
    __syncthreads();
  }

  float* Cz = Cpart + (long)z * NTOK * DD;
  const int orow0 = (lane >> 4) * 4;
#pragma unroll
  for (int mi = 0; mi < 4; ++mi) {
    long gr = rowBase + wr * 64 + mi * 16 + orow0;
#pragma unroll
    for (int ni = 0; ni < 4; ++ni) {
      long gc = colBase + wc * 64 + ni * 16 + fr;
#pragma unroll
      for (int r = 0; r < 4; ++r)
        Cz[(gr + r) * (long)N + gc] = acc[mi][ni][r];
    }
  }
}

// ------- reduce partials, applying the folded-LN affine per branch ----------
__global__ __launch_bounds__(256) void reduce_out(const float* __restrict__ P,
                                                  const float* __restrict__ bias,
                                                  const float* __restrict__ sumb,
                                                  const float* __restrict__ sqb,
                                                  const float* __restrict__ Sbuf,
                                                  const float* __restrict__ Tbuf,
                                                  const float* __restrict__ fw,
                                                  float* __restrict__ out) {
  long i = (long)blockIdx.x * 256 + threadIdx.x;   // over NTOK*DD/4 f32x4
  int r = (int)(i / (DD / 4));
  int c4 = (int)(i % (DD / 4));
  int b = r >> 11;
  f32x4 o = *(const f32x4*)(bias + c4 * 4);
#pragma unroll
  for (int br = 0; br < 3; ++br) {
    float sum = sumb[br * NTOK + r];
    float sq  = sqb[br * NTOK + r];
    float mean = sum * (1.f / (float)DD);
    float var  = sq * (1.f / (float)DD) - mean * mean;
    float rs   = rsqrtf(var + 1e-5f);
    float gate = fw[b * 3 + br];
    f32x4 P4 = ((const f32x4*)(P + (long)br * NTOK * DD))[i];
    f32x4 S4 = *(const f32x4*)(Sbuf + br * DD + c4 * 4);
    f32x4 T4 = *(const f32x4*)(Tbuf + br * DD + c4 * 4);
#pragma unroll
    for (int e = 0; e < 4; ++e)
      o[e] += gate * (rs * (P4[e] - mean * S4[e]) + T4[e]);
  }
  ((f32x4*)out)[i] = o;
}

// ---------------- attention bodies (raw bf16 output + row stats) ------------
__device__ __forceinline__ void attn_flash_body(
    const unsigned short* __restrict__ QKV4,
    const unsigned short* __restrict__ KVg,
    const unsigned short* __restrict__ Vt,
    unsigned short* __restrict__ comb,
    float* __restrict__ sumb, float* __restrict__ sqb,
    unsigned short* smem) {
  unsigned short* Kl = smem;            // [2][64*64]
  unsigned short* Vl = smem + 8192;     // [2][64*64]
  unsigned short* Pl = smem + 16384;    // [4][16*68]
  int tid = threadIdx.x, w = tid >> 6, lane = tid & 63;
  int fr = lane & 15, g = lane >> 4;
  int b = blockIdx.y / HH, h = blockIdx.y % HH, hoff = h * 64;
  int qbase = blockIdx.x * 64 + w * 16;
  long qrow = (long)b * SS + qbase + fr;

  const unsigned short* qptr = QKV4 + qrow * 3072 + hoff + g * 8;
  bf16x8 bq0 = *(const bf16x8*)(qptr);
  bf16x8 bq1 = *(const bf16x8*)(qptr + 32);

  const int s0 = tid, s1 = tid + 256;
  const int r0 = s0 >> 3, c0 = (s0 & 7) ^ (r0 & 7);
  const int r1 = s1 >> 3, c1 = (s1 & 7) ^ (r1 & 7);
  const unsigned short* kg_b = KVg + (long)b * KPAD * 1536 + hoff;
  const unsigned short* vt_b = Vt + ((long)b * DD + hoff) * KPAD;

  auto stage = [&](int buf, int t0) {
    gload_lds16(kg_b + (long)(t0 * 64 + r0) * 1536 + c0 * 8, &Kl[buf * 4096 + s0 * 8]);
    gload_lds16(kg_b + (long)(t0 * 64 + r1) * 1536 + c1 * 8, &Kl[buf * 4096 + s1 * 8]);
    gload_lds16(vt_b + (long)r0 * KPAD + t0 * 64 + c0 * 8, &Vl[buf * 4096 + s0 * 8]);
    gload_lds16(vt_b + (long)r1 * KPAD + t0 * 64 + c1 * 8, &Vl[buf * 4096 + s1 * 8]);
  };

  f32x4 oacc[4];
#pragma unroll
  for (int mf = 0; mf < 4; ++mf)
#pragma unroll
    for (int r = 0; r < 4; ++r) oacc[mf][r] = 0.f;
  float m = -3.0e38f, l = 0.f;

  stage(0, 0);
  asm volatile("s_waitcnt vmcnt(0)" ::: "memory");
  __syncthreads();

  for (int t = 0; t < NKT; ++t) {
    int cur = t & 1;
    if (t + 1 < NKT) stage(cur ^ 1, t + 1);

    f32x4 st[4];
#pragma unroll
    for (int kt = 0; kt < 4; ++kt) {
      int row = kt * 16 + fr;
      bf16x8 a0 = *(const bf16x8*)(&Kl[cur * 4096 + (row * 8 + (g ^ (row & 7))) * 8]);
      bf16x8 a1 = *(const bf16x8*)(&Kl[cur * 4096 + (row * 8 + ((4 + g) ^ (row & 7))) * 8]);
      f32x4 z = {0.f, 0.f, 0.f, 0.f};
      z = __builtin_amdgcn_mfma_f32_16x16x32_bf16(a0, bq0, z, 0, 0, 0);
      st[kt] = __builtin_amdgcn_mfma_f32_16x16x32_bf16(a1, bq1, z, 0, 0, 0);
    }

    float tm = -3.0e38f;
#pragma unroll
    for (int kt = 0; kt < 4; ++kt)
#pragma unroll
      for (int r = 0; r < 4; ++r) {
        int key = t * 64 + kt * 16 + g * 4 + r;
        float s = (key < KSEL) ? st[kt][r] * 0.125f : -1.0e30f;
        st[kt][r] = s;
        tm = fmaxf(tm, s);
      }
    tm = fmaxf(tm, __shfl_xor(tm, 16, 64));
    tm = fmaxf(tm, __shfl_xor(tm, 32, 64));
    float newm = fmaxf(m, tm);
    float f = __expf(m - newm);
    float tsum = 0.f;
#pragma unroll
    for (int kt = 0; kt < 4; ++kt)
#pragma unroll
      for (int r = 0; r < 4; ++r) {
        float e = __expf(st[kt][r] - newm);
        st[kt][r] = e;
        tsum += e;
      }
    tsum += __shfl_xor(tsum, 16, 64);
    tsum += __shfl_xor(tsum, 32, 64);
    l = l * f + tsum;
    m = newm;
#pragma unroll
    for (int mf = 0; mf < 4; ++mf)
#pragma unroll
      for (int r = 0; r < 4; ++r) oacc[mf][r] *= f;

    unsigned short* pw = &Pl[w * 1088 + fr * 68 + g * 4];
#pragma unroll
    for (int kt = 0; kt < 4; ++kt) {
      uint2 pk;
      pk.x = (unsigned)f2b(st[kt][0]) | ((unsigned)f2b(st[kt][1]) << 16);
      pk.y = (unsigned)f2b(st[kt][2]) | ((unsigned)f2b(st[kt][3]) << 16);
      *(uint2*)(pw + kt * 16) = pk;
    }

    const unsigned short* prd = &Pl[w * 1088 + fr * 68];
#pragma unroll
    for (int ks2 = 0; ks2 < 2; ++ks2) {
      bf16x8 pf = *(const bf16x8*)(prd + ks2 * 32 + g * 8);
#pragma unroll
      for (int mf = 0; mf < 4; ++mf) {
        int vr = mf * 16 + fr;
        int vc = ks2 * 4 + g;
        bf16x8 vf = *(const bf16x8*)(&Vl[cur * 4096 + (vr * 8 + (vc ^ (vr & 7))) * 8]);
        oacc[mf] = __builtin_amdgcn_mfma_f32_16x16x32_bf16(vf, pf, oacc[mf], 0, 0, 0);
      }
    }

    asm volatile("s_waitcnt vmcnt(0)" ::: "memory");
    __syncthreads();
  }

  float inv = 1.f / l;
  unsigned short* orow = comb + qrow * 2304 + hoff;
  float rsum = 0.f, rsq = 0.f;
#pragma unroll
  for (int mf = 0; mf < 4; ++mf) {
    float v0 = oacc[mf][0] * inv, v1 = oacc[mf][1] * inv;
    float v2 = oacc[mf][2] * inv, v3 = oacc[mf][3] * inv;
    rsum += v0 + v1 + v2 + v3;
    rsq  += v0 * v0 + v1 * v1 + v2 * v2 + v3 * v3;
    uint2 pk;
    pk.x = (unsigned)f2b(v0) | ((unsigned)f2b(v1) << 16);
    pk.y = (unsigned)f2b(v2) | ((unsigned)f2b(v3) << 16);
    *(uint2*)(orow + mf * 16 + g * 4) = pk;
  }
  rsum += __shfl_xor(rsum, 16, 64);
  rsum += __shfl_xor(rsum, 32, 64);
  rsq  += __shfl_xor(rsq, 16, 64);
  rsq  += __shfl_xor(rsq, 32, 64);
  if (lane < 16) {
    atomicAdd(&sumb[qrow], rsum);
    atomicAdd(&sqb[qrow], rsq);
  }
}

__device__ __forceinline__ void attn_win_body(
    const unsigned short* __restrict__ QKV,
    const unsigned short* __restrict__ K8,
    const unsigned short* __restrict__ Vt,
    unsigned short* __restrict__ comb, int brOff,
    float* __restrict__ sumb, float* __restrict__ sqb,
    int LD, int QO, long VSTR, bool local,
    unsigned short* smem) {
  int tid = threadIdx.x, w = tid >> 6, lane = tid & 63;
  int fr = lane & 15, g = lane >> 4;
  int b = blockIdx.y / HH, h = blockIdx.y % HH, hoff = h * 64;
  int qbase = blockIdx.x * 64 + w * 16;
  long qrow = (long)b * SS + qbase + fr;

  const unsigned short* qptr = QKV + qrow * LD + QO + hoff + g * 8;
  bf16x8 bq0 = *(const bf16x8*)(qptr);
  bf16x8 bq1 = *(const bf16x8*)(qptr + 32);

  int kstart = qbase - 8;
  if (kstart < 0) kstart = 0;
  if (kstart > SS - 32) kstart = SS - 32;

  f32x4 st[2];
  if (local) {
#pragma unroll
    for (int kt = 0; kt < 2; ++kt) {
      const unsigned short* kp =
          QKV + ((long)b * SS + kstart + kt * 16 + fr) * LD + 1536 + hoff + g * 8;
      bf16x8 a0 = *(const bf16x8*)(kp);
      bf16x8 a1 = *(const bf16x8*)(kp + 32);
      f32x4 z = {0.f, 0.f, 0.f, 0.f};
      z = __builtin_amdgcn_mfma_f32_16x16x32_bf16(a0, bq0, z, 0, 0, 0);
      st[kt] = __builtin_amdgcn_mfma_f32_16x16x32_bf16(a1, bq1, z, 0, 0, 0);
    }
  } else {
    const unsigned short* kp = K8 + ((long)b * 16 + fr) * DD + hoff + g * 8;
    bf16x8 a0 = *(const bf16x8*)(kp);
    bf16x8 a1 = *(const bf16x8*)(kp + 32);
    f32x4 z = {0.f, 0.f, 0.f, 0.f};
    z = __builtin_amdgcn_mfma_f32_16x16x32_bf16(a0, bq0, z, 0, 0, 0);
    st[0] = __builtin_amdgcn_mfma_f32_16x16x32_bf16(a1, bq1, z, 0, 0, 0);
    st[1] = f32x4{0.f, 0.f, 0.f, 0.f};
  }

  float m = -3.0e38f;
#pragma unroll
  for (int kt = 0; kt < 2; ++kt)
#pragma unroll
    for (int r = 0; r < 4; ++r) {
      int idx = kt * 16 + g * 4 + r;
      bool valid;
      if (local) {
        int rel = kstart + idx - qbase - fr;
        valid = (rel >= -8) && (rel <= 8);
      } else {
        valid = (idx < 8);
      }
      float s = valid ? st[kt][r] * 0.125f : -1.0e30f;
      st[kt][r] = s;
      m = fmaxf(m, s);
    }
  m = fmaxf(m, __shfl_xor(m, 16, 64));
  m = fmaxf(m, __shfl_xor(m, 32, 64));

  float lsum = 0.f;
#pragma unroll
  for (int kt = 0; kt < 2; ++kt)
#pragma unroll
    for (int r = 0; r < 4; ++r) {
      float e = __expf(st[kt][r] - m);
      st[kt][r] = e;
      lsum += e;
    }
  lsum += __shfl_xor(lsum, 16, 64);
  lsum += __shfl_xor(lsum, 32, 64);

  unsigned short* pl = smem + w * 640 + fr * 40 + g * 4;
#pragma unroll
  for (int kt = 0; kt < 2; ++kt) {
    uint2 pk;
    pk.x = (unsigned)f2b(st[kt][0]) | ((unsigned)f2b(st[kt][1]) << 16);
    pk.y = (unsigned)f2b(st[kt][2]) | ((unsigned)f2b(st[kt][3]) << 16);
    *(uint2*)(pl + kt * 16) = pk;
  }

  f32x4 oacc[4];
#pragma unroll
  for (int mf = 0; mf < 4; ++mf)
#pragma unroll
    for (int r = 0; r < 4; ++r) oacc[mf][r] = 0.f;

  const unsigned short* pr = smem + w * 640 + fr * 40 + g * 8;
  bf16x8 pf = *(const bf16x8*)(pr);
  long kb2 = local ? kstart : 0;
#pragma unroll
  for (int mf = 0; mf < 4; ++mf) {
    const unsigned short* vp =
        Vt + ((long)b * DD + hoff + mf * 16 + fr) * VSTR + kb2 + g * 8;
    bf16x8 vf = *(const bf16x8*)(vp);
    oacc[mf] = __builtin_amdgcn_mfma_f32_16x16x32_bf16(vf, pf, oacc[mf], 0, 0, 0);
  }

  float inv = 1.f / lsum;
  unsigned short* orow = comb + qrow * 2304 + brOff + hoff;
  float rsum = 0.f, rsq = 0.f;
#pragma unroll
  for (int mf = 0; mf < 4; ++mf) {
    float v0 = oacc[mf][0] * inv, v1 = oacc[mf][1] * inv;
    float v2 = oacc[mf][2] * inv, v3 = oacc[mf][3] * inv;
    rsum += v0 + v1 + v2 + v3;
    rsq  += v0 * v0 + v1 * v1 + v2 * v2 + v3 * v3;
    uint2 pk;
    pk.x = (unsigned)f2b(v0) | ((unsigned)f2b(v1) << 16);
    pk.y = (unsigned)f2b(v2) | ((unsigned)f2b(v3) << 16);
    *(uint2*)(orow + mf * 16 + g * 4) = pk;
  }
  rsum += __shfl_xor(rsum, 16, 64);
  rsum += __shfl_xor(rsum, 32, 64);
  rsq  += __shfl_xor(rsq, 16, 64);
  rsq  += __shfl_xor(rsq, 32, 64);
  if (lane < 16) {
    atomicAdd(&sumb[qrow], rsum);
    atomicAdd(&sqb[qrow], rsq);
  }
}

// ---------------- merged attention dispatch (z: 0=global 1=local 2=temporal)
__global__ __launch_bounds__(256) void attn_all(
    const unsigned short* __restrict__ QKV4,
    const unsigned short* __restrict__ KVg,
    const unsigned short* __restrict__ Vt,
    const unsigned short* __restrict__ Qt,
    const unsigned short* __restrict__ K8,
    const unsigned short* __restrict__ Vt8,
    const unsigned short* __restrict__ Vtl,
    unsigned short* __restrict__ comb,
    float* __restrict__ sumb, float* __restrict__ sqb) {
  __shared__ unsigned short smem[20736];
  int z = blockIdx.z;
  if (z == 0) {
    attn_flash_body(QKV4, KVg, Vt, comb, sumb, sqb, smem);
  } else if (z == 1) {
    attn_win_body(QKV4, nullptr, Vtl, comb, 768, sumb + NTOK, sqb + NTOK,
                  3072, 768, SS, true, smem);
  } else {
    attn_win_body(Qt, K8, Vt8, comb, 1536, sumb + 2 * NTOK, sqb + 2 * NTOK,
                  768, 0, 32, false, smem);
  }
}

// ---------------- launcher ---------------------------------------------------
extern "C" void kernel_launch(void* const* d_in, const int* in_sizes, int n_in,
                              void* d_out, int out_size, void* d_ws, size_t ws_size,
                              hipStream_t stream) {
  const float* x        = (const float*)d_in[0];
  const float* wgq      = (const float*)d_in[1];
  const float* wgk      = (const float*)d_in[2];
  const float* wgv      = (const float*)d_in[3];
  const float* wlq      = (const float*)d_in[4];
  const float* wlk      = (const float*)d_in[5];
  const float* wlv      = (const float*)d_in[6];
  const float* wtq      = (const float*)d_in[7];
  const float* wtk      = (const float*)d_in[8];
  const float* wtv      = (const float*)d_in[9];
  const float* w_out    = (const float*)d_in[10];
  const float* b_out    = (const float*)d_in[11];
  const float* w_gate   = (const float*)d_in[12];
  const float* b_gate   = (const float*)d_in[13];
  const float* w_sparse = (const float*)d_in[14];
  const float* b_sparse = (const float*)d_in[15];
  const float* g_gamma  = (const float*)d_in[16];
  const float* g_beta   = (const float*)d_in[17];
  const float* l_gamma  = (const float*)d_in[18];
  const float* l_beta   = (const float*)d_in[19];
  const float* t_gamma  = (const float*)d_in[20];
  const float* t_beta   = (const float*)d_in[21];
  float* outp = (float*)d_out;

  unsigned short* xb    = (unsigned short*)d_ws;
  unsigned short* xpb   = xb    + (long)NTOK * DD;
  unsigned short* WTx4  = xpb   + (long)NTOK * DD;        // [3072][768]
  unsigned short* WTkv  = WTx4  + (long)3072 * DD;        // [1536][768]
  unsigned short* WTqt  = WTkv  + (long)1536 * DD;        // [768][768]
  unsigned short* WTtkv = WTqt  + (long)DD * DD;          // [1536][768]
  unsigned short* WTo   = WTtkv + (long)1536 * DD;        // [768][2304] (gamma-folded)
  unsigned short* QKV4  = WTo   + (long)DD * 2304;        // [4096][3072]
  unsigned short* Qt    = QKV4  + (long)NTOK * 3072;      // [4096][768]
  unsigned short* KVg   = Qt    + (long)NTOK * DD;        // [896][1536]
  unsigned short* K8    = KVg   + (long)BB * KPAD * 1536; // [2][16][768]
  unsigned short* Vt8   = K8    + (long)BB * 16 * DD;     // [2][768][32]
  unsigned short* Vt    = Vt8   + (long)BB * DD * 32;     // [2][768][448]
  unsigned short* Vtl   = Vt    + (long)BB * DD * KPAD;   // [2][768][2048]
  unsigned short* comb  = Vtl   + (long)BB * DD * SS;     // [4096][2304] raw attn
  float* Cpart   = (float*)(comb + (long)NTOK * 2304);    // [3][4096][768]
  float* imp     = Cpart + 3L * NTOK * DD;
  float* partial = imp + NTOK;
  float* fw      = partial + 32 * DD;
  int*   sel     = (int*)(fw + 8);
  float* sumb    = (float*)(sel + 1024);                  // [3][4096]
  float* sqb     = sumb + 3 * NTOK;                       // [3][4096]
  float* Sbuf    = sqb + 3 * NTOK;                        // [3][768]
  float* Tbuf    = Sbuf + 3 * DD;                         // [3][768]

  hipMemsetAsync(sumb, 0, (size_t)(6 * NTOK + 6 * DD) * sizeof(float), stream);

  mega_pre<<<SS + 6912 + 32, 256, 0, stream>>>(
      x, w_sparse, b_sparse, xb, xpb, imp,
      wgq, wgk, wgv, wlq, wlk, wlv, wtq, wtk, wtv, w_out,
      g_gamma, l_gamma, t_gamma, g_beta, l_beta, t_beta,
      WTx4, WTkv, WTqt, WTtkv, WTo, Sbuf, Tbuf, partial);
  topk_gate2<<<4, 1024, 0, stream>>>(imp, sel, partial, w_gate, b_gate, fw);

  gemm_multi<<<1056, 256, 0, stream>>>(xb, WTx4, QKV4, WTkv, KVg,
                                       xpb, WTqt, Qt, WTtkv, sel,
                                       K8, Vt8, Vt, Vtl);

  attn_all<<<dim3(32, BB * HH, 3), 256, 0, stream>>>(QKV4, KVg, Vt, Qt, K8, Vt8,
                                                     Vtl, comb, sumb, sqb);

  gemm_final_sk<<<dim3(6, 32, 3), 256, 0, stream>>>(comb, WTo, Cpart);
  reduce_out<<<NTOK * DD / 4 / 256, 256, 0, stream>>>(Cpart, b_out, sumb, sqb,
                                                      Sbuf, Tbuf, fw, outp);
}